// Round 4
// baseline (1144.082 us; speedup 1.0000x reference)
//
#include <hip/hip_runtime.h>
#include <stdint.h>

#define PN 8192
#define SN 8192
#define KNB 16
#define NCHUNK 4
#define CHUNK (PN / NCHUNK)

#define KEY_SENTINEL ((long long)0x8000000000000000ULL)
#define PD_SCALE 2199023255552.0   // 2^41: |pd|<256 -> |scaled|<2^49; <<13 fits i64

// ---------------- kernel 0: pack points (x,y,z,0) ----------------
__global__ void pack_pts_kernel(const float* __restrict__ x, float4* __restrict__ pts) {
    int i = blockIdx.x * 256 + threadIdx.x;           // 0 .. 2*PN-1
    int b = i >> 13, p = i & (PN - 1);
    const float* xb = x + (size_t)b * 4 * PN;
    pts[i] = make_float4(xb[p], xb[PN + p], xb[2 * PN + p], 0.f);
}

// ---------------- kernel 1: stable argsort via bitonic sort of (key,idx) ----------------
__global__ __launch_bounds__(1024) void argsort_kernel(const float* __restrict__ rnd,
                                                       int* __restrict__ perm) {
    __shared__ unsigned long long keys[PN];           // 64 KB
    const int b = blockIdx.x;
    const float* r = rnd + b * PN;
    for (int i = threadIdx.x; i < PN; i += 1024) {
        // rand in [0,1) is non-negative -> raw bits are order-preserving.
        keys[i] = ((unsigned long long)__float_as_uint(r[i]) << 32) | (unsigned)i;
    }
    __syncthreads();
    for (int k = 2; k <= PN; k <<= 1) {
        for (int j = k >> 1; j > 0; j >>= 1) {
            for (int t = threadIdx.x; t < PN; t += 1024) {
                int ixj = t ^ j;
                if (ixj > t) {
                    unsigned long long a = keys[t], c = keys[ixj];
                    bool up = ((t & k) == 0);
                    if ((a > c) == up) { keys[t] = c; keys[ixj] = a; }
                }
            }
            __syncthreads();
        }
    }
    for (int i = threadIdx.x; i < PN; i += 1024)
        perm[b * PN + i] = (int)(keys[i] & 0xffffffffull);
}

// ---------------- kernel 2: per-chunk top-16 in exact (f64) distance order ----------------
// thread = one sample. Candidate key: (floor(-dd * 2^41) << 13) | (8191 - p).
// Monotone in true distance (res 4.5e-13), tie -> smaller p. Matches top_k semantics
// against the true ranking; f64 from f32 inputs is effectively exact.
__global__ __launch_bounds__(256) void knn_partial_kernel(const float4* __restrict__ pts,
        const int* __restrict__ perm, long long* __restrict__ partK) {
    __shared__ float4 lp[CHUNK];                      // 32 KB
    const int chunk = blockIdx.x, sg = blockIdx.y, b = blockIdx.z;
    const float4* pb = pts + b * PN;
    const int pbase = chunk * CHUNK;
    for (int i = threadIdx.x; i < CHUNK; i += 256) lp[i] = pb[pbase + i];
    __syncthreads();
    const int s = sg * 256 + threadIdx.x;
    const float4 qp = pb[perm[b * PN + s]];
    const double qx = qp.x, qy = qp.y, qz = qp.z;
    long long kv[KNB];
#pragma unroll
    for (int i = 0; i < KNB; ++i) kv[i] = KEY_SENTINEL;
    for (int c = 0; c < CHUNK; ++c) {
        float4 pp = lp[c];
        double dx = qx - (double)pp.x;
        double dy = qy - (double)pp.y;
        double dz = qz - (double)pp.z;
        double dd = dx * dx + dy * dy + dz * dz;
        long long sc = (long long)floor(-dd * PD_SCALE);
        long long kk = (sc << 13) | (long long)(8191 - (pbase + c));
        if (kk > kv[KNB - 1]) {
#pragma unroll
            for (int i = KNB - 1; i > 0; --i) {
                bool shift = kk > kv[i - 1];
                kv[i] = shift ? kv[i - 1] : ((kk > kv[i]) ? kk : kv[i]);
            }
            if (kk > kv[0]) kv[0] = kk;
        }
    }
    long long* ok = partK + ((size_t)(b * NCHUNK + chunk) * SN + s) * KNB;
#pragma unroll
    for (int i = 0; i < KNB; ++i) ok[i] = kv[i];
}

// ---------------- kernel 3: merge 4 sorted chunk-lists, write knn[b][rank][s] ----------------
__global__ void knn_merge_kernel(const long long* __restrict__ partK, int* __restrict__ knn) {
    int t = blockIdx.x * 256 + threadIdx.x;           // 0 .. 2*SN-1
    int b = t >> 13, s = t & (SN - 1);
    const long long* K0 = partK + ((size_t)(b * NCHUNK + 0) * SN + s) * KNB;
    const long long* K1 = partK + ((size_t)(b * NCHUNK + 1) * SN + s) * KNB;
    const long long* K2 = partK + ((size_t)(b * NCHUNK + 2) * SN + s) * KNB;
    const long long* K3 = partK + ((size_t)(b * NCHUNK + 3) * SN + s) * KNB;
    long long h0 = K0[0], h1 = K1[0], h2 = K2[0], h3 = K3[0];
    int p0 = 1, p1 = 1, p2 = 1, p3 = 1;
    int* ob = knn + (size_t)b * (SN * KNB);
    for (int r = 0; r < KNB; ++r) {
        long long m01 = h0 > h1 ? h0 : h1;
        long long m23 = h2 > h3 ? h2 : h3;
        long long m = m01 > m23 ? m01 : m23;
        ob[(size_t)r * SN + s] = 8191 - (int)(m & 8191);
        if (m == h0)      { h0 = (p0 < KNB) ? K0[p0] : KEY_SENTINEL; ++p0; }
        else if (m == h1) { h1 = (p1 < KNB) ? K1[p1] : KEY_SENTINEL; ++p1; }
        else if (m == h2) { h2 = (p2 < KNB) ? K2[p2] : KEY_SENTINEL; ++p2; }
        else              { h3 = (p3 < KNB) ? K3[p3] : KEY_SENTINEL; ++p3; }
    }
}

// ---------------- kernel 4: GroupNorm statistics ----------------
// lane l owns channel l (0..31 conv, 32..63 pe); wave accumulates sum & sumsq over positions.
__global__ __launch_bounds__(256) void stats_kernel(const float* __restrict__ x,
        const int* __restrict__ knn, const float* __restrict__ w_pe,
        const float* __restrict__ w_conv, float* __restrict__ wavepart) {
    const int blk = blockIdx.x;                       // 0..255
    const int b = blockIdx.y;
    const int w = threadIdx.x >> 6, l = threadIdx.x & 63;
    float wr[10];
#pragma unroll
    for (int c = 0; c < 10; ++c) wr[c] = 0.f;
    if (l < 32) {
#pragma unroll
        for (int c = 0; c < 4; ++c) wr[c] = w_conv[l * 4 + c];
    } else {
#pragma unroll
        for (int c = 0; c < 10; ++c) wr[c] = w_pe[(l - 32) * 10 + c];
    }
    const float* xb = x + (size_t)b * 4 * PN;
    const int* kb = knn + (size_t)b * (SN * KNB);
    float s1 = 0.f, s2 = 0.f;
    const int nbase = blk * 512 + w * 128;
#pragma unroll 2
    for (int it = 0; it < 128; ++it) {
        int n = nbase + it;
        int i  = kb[n];
        int i0 = kb[n & ~15];
        float xa0 = xb[i], xa1 = xb[PN + i], xa2 = xb[2 * PN + i], xa3 = xb[3 * PN + i];
        float xc0 = xb[i0], xc1 = xb[PN + i0], xc2 = xb[2 * PN + i0];
        float d0 = xa0 - xc0, d1 = xa1 - xc1, d2 = xa2 - xc2;
        float dd = d0 * d0; dd += d1 * d1; dd += d2 * d2;
        float temp = sqrtf(fmaxf(dd, 1e-12f));
        float r;
        if (l < 32) {
            r = wr[0] * xa0 + wr[1] * xa1 + wr[2] * xa2 + wr[3] * xa3;
        } else {
            r = wr[0] * xa0 + wr[1] * xa1 + wr[2] * xa2
              + wr[3] * xc0 + wr[4] * xc1 + wr[5] * xc2
              + wr[6] * d0 + wr[7] * d1 + wr[8] * d2 + wr[9] * temp;
        }
        s1 += r;
        s2 += r * r;
    }
    const int wslot = blk * 4 + w;                    // 0..1023
    wavepart[((size_t)b * 1024 + wslot) * 128 + l] = s1;
    wavepart[((size_t)b * 1024 + wslot) * 128 + 64 + l] = s2;
}

// ---------------- kernel 5: finalize stats -> per-channel scale/shift ----------------
__global__ void finalize_kernel(const float* __restrict__ wavepart,
        const float* __restrict__ g_pe, const float* __restrict__ b_pe,
        const float* __restrict__ g_conv, const float* __restrict__ b_conv,
        float* __restrict__ scsh) {
    const int t = threadIdx.x;                        // 0..255
    const int b = t >> 7, k = t & 127;
    float acc = 0.f;
    for (int w = 0; w < 1024; ++w) acc += wavepart[((size_t)b * 1024 + w) * 128 + k];
    __shared__ float sums[2][128];
    sums[b][k] = acc;
    __syncthreads();
    if (k < 64) {
        const float N = 131072.f;
        float mean = sums[b][k] / N;
        float var = sums[b][64 + k] / N - mean * mean;
        float rstd = 1.0f / sqrtf(var + 1e-5f);
        float gam = (k < 32) ? g_conv[k] : g_pe[k - 32];
        float bet = (k < 32) ? b_conv[k] : b_pe[k - 32];
        float sc = gam * rstd;
        scsh[(b * 64 + k) * 2 + 0] = sc;
        scsh[(b * 64 + k) * 2 + 1] = bet - mean * sc;
    }
}

// ---------------- kernel 6: fused feature/attention/output ----------------
// lane = (group g = l>>4 -> sample, j = l&15 -> neighbor). 16 samples per 256-thread block.
__global__ __launch_bounds__(256) void fused_main_kernel(
        const float* __restrict__ x, const int* __restrict__ knn,
        const float* __restrict__ w_pe, const float* __restrict__ w_conv,
        const float* __restrict__ w_att1, const float* __restrict__ w_att2,
        const float* __restrict__ w_b1, const float* __restrict__ w_b2,
        const float* __restrict__ scsh, float* __restrict__ out) {
    __shared__ float wb1T[64 * 64];                   // [c][o]
    __shared__ float wb2T[4 * 64];                    // [c][o]
    for (int i = threadIdx.x; i < 64 * 64; i += 256) wb1T[(i & 63) * 64 + (i >> 6)] = w_b1[i];
    { int i = threadIdx.x; wb2T[(i & 3) * 64 + (i >> 2)] = w_b2[i]; }
    __syncthreads();
    const int gidx = blockIdx.x;                      // 0..1023
    const int b = gidx >> 9;
    const int sb = (gidx & 511) << 4;
    const int l = threadIdx.x & 63;
    const int w = threadIdx.x >> 6;
    const int g = l >> 4, j = l & 15;
    const int s = sb + (w << 2) + g;
    const int srcl = g << 4;
    const float* xb = x + (size_t)b * 4 * PN;
    const int i1 = knn[(size_t)b * (SN * KNB) + (size_t)s * KNB + j];
    float xa0 = xb[i1], xa1 = xb[PN + i1], xa2 = xb[2 * PN + i1], xa3 = xb[3 * PN + i1];
    float xc0 = __shfl(xa0, srcl), xc1 = __shfl(xa1, srcl);
    float xc2 = __shfl(xa2, srcl), xc3 = __shfl(xa3, srcl);
    float d0 = xa0 - xc0, d1 = xa1 - xc1, d2 = xa2 - xc2;
    float dd = d0 * d0; dd += d1 * d1; dd += d2 * d2;
    float temp = sqrtf(fmaxf(dd, 1e-12f));
    float pem[10] = {xa0, xa1, xa2, xc0, xc1, xc2, d0, d1, d2, temp};
    float f[64];
    const float* ssb = scsh + b * 128;
#pragma unroll
    for (int o = 0; o < 32; ++o) {
        float r = w_conv[o * 4 + 0] * xa0;
        r += w_conv[o * 4 + 1] * xa1;
        r += w_conv[o * 4 + 2] * xa2;
        r += w_conv[o * 4 + 3] * xa3;
        r = r * ssb[o * 2 + 0] + ssb[o * 2 + 1];
        f[o] = (r >= 0.f) ? r : 0.2f * r;
    }
#pragma unroll
    for (int o = 0; o < 32; ++o) {
        float r = 0.f;
#pragma unroll
        for (int c = 0; c < 10; ++c) r += w_pe[o * 10 + c] * pem[c];
        r = r * ssb[(32 + o) * 2 + 0] + ssb[(32 + o) * 2 + 1];
        f[32 + o] = (r >= 0.f) ? r : 0.2f * r;
    }
    float logit = 0.f;
#pragma unroll 2
    for (int o = 0; o < 32; ++o) {
        float a = 0.f;
#pragma unroll
        for (int c = 0; c < 64; ++c) a += w_att1[o * 64 + c] * f[c];
        a = (a >= 0.f) ? a : 0.2f * a;
        logit += w_att2[o] * a;
    }
    // softmax over the 16 neighbors (lanes of the group)
    float mx = logit;
    mx = fmaxf(mx, __shfl_xor(mx, 1));
    mx = fmaxf(mx, __shfl_xor(mx, 2));
    mx = fmaxf(mx, __shfl_xor(mx, 4));
    mx = fmaxf(mx, __shfl_xor(mx, 8));
    float e = expf(logit - mx);
    float se = e;
    se += __shfl_xor(se, 1);
    se += __shfl_xor(se, 2);
    se += __shfl_xor(se, 4);
    se += __shfl_xor(se, 8);
    float att = e / se;
    // attention-weighted feature sum across the group
#pragma unroll
    for (int c = 0; c < 64; ++c) {
        float v = f[c] * att;
        v += __shfl_xor(v, 1);
        v += __shfl_xor(v, 2);
        v += __shfl_xor(v, 4);
        v += __shfl_xor(v, 8);
        f[c] = v;
    }
    // Fea1 + Fea2, outputs o = 4j..4j+3
    float o0 = 0.f, o1 = 0.f, o2 = 0.f, o3 = 0.f;
#pragma unroll
    for (int c = 0; c < 64; ++c) {
        float4 wv = *reinterpret_cast<const float4*>(&wb1T[c * 64 + 4 * j]);
        o0 += wv.x * f[c]; o1 += wv.y * f[c]; o2 += wv.z * f[c]; o3 += wv.w * f[c];
    }
    {
        float4 wv = *reinterpret_cast<const float4*>(&wb2T[0 * 64 + 4 * j]);
        o0 += wv.x * xc0; o1 += wv.y * xc0; o2 += wv.z * xc0; o3 += wv.w * xc0;
        wv = *reinterpret_cast<const float4*>(&wb2T[1 * 64 + 4 * j]);
        o0 += wv.x * xc1; o1 += wv.y * xc1; o2 += wv.z * xc1; o3 += wv.w * xc1;
        wv = *reinterpret_cast<const float4*>(&wb2T[2 * 64 + 4 * j]);
        o0 += wv.x * xc2; o1 += wv.y * xc2; o2 += wv.z * xc2; o3 += wv.w * xc2;
        wv = *reinterpret_cast<const float4*>(&wb2T[3 * 64 + 4 * j]);
        o0 += wv.x * xc3; o1 += wv.y * xc3; o2 += wv.z * xc3; o3 += wv.w * xc3;
    }
    o0 = (o0 >= 0.f) ? o0 : 0.1f * o0;
    o1 = (o1 >= 0.f) ? o1 : 0.1f * o1;
    o2 = (o2 >= 0.f) ? o2 : 0.1f * o2;
    o3 = (o3 >= 0.f) ? o3 : 0.1f * o3;
    float* ob = out + (size_t)b * 67 * SN;
    const int oc = 3 + 4 * j;
    ob[(size_t)(oc + 0) * SN + s] = o0;
    ob[(size_t)(oc + 1) * SN + s] = o1;
    ob[(size_t)(oc + 2) * SN + s] = o2;
    ob[(size_t)(oc + 3) * SN + s] = o3;
    if (j < 3) ob[(size_t)j * SN + s] = (j == 0) ? xc0 : ((j == 1) ? xc1 : xc2);
}

extern "C" void kernel_launch(void* const* d_in, const int* in_sizes, int n_in,
                              void* d_out, int out_size, void* d_ws, size_t ws_size,
                              hipStream_t stream) {
    (void)in_sizes; (void)n_in; (void)out_size; (void)ws_size;
    const float* x      = (const float*)d_in[0];
    const float* rnd    = (const float*)d_in[1];
    const float* w_pe   = (const float*)d_in[2];
    const float* g_pe   = (const float*)d_in[3];
    const float* b_pe   = (const float*)d_in[4];
    const float* w_conv = (const float*)d_in[5];
    const float* g_conv = (const float*)d_in[6];
    const float* b_conv = (const float*)d_in[7];
    const float* w_att1 = (const float*)d_in[8];
    const float* w_att2 = (const float*)d_in[9];
    const float* w_b1   = (const float*)d_in[10];
    const float* w_b2   = (const float*)d_in[11];
    float* out = (float*)d_out;
    char* ws = (char*)d_ws;
    // workspace carve-up (bytes), total ~10.8 MB (identical footprint to prev round)
    float4*    pts    = (float4*)   (ws + 0);         //   262,144
    int*       perm   = (int*)      (ws + 262144);    //    65,536
    long long* partK  = (long long*)(ws + 327680);    // 8,388,608 (replaces partV+partI)
    int*       knn    = (int*)      (ws + 8716288);   // 1,048,576
    float*     wavept = (float*)    (ws + 9764864);   // 1,048,576
    float*     scsh   = (float*)    (ws + 10813440);  //     1,024

    pack_pts_kernel<<<64, 256, 0, stream>>>(x, pts);
    argsort_kernel<<<2, 1024, 0, stream>>>(rnd, perm);
    knn_partial_kernel<<<dim3(NCHUNK, 32, 2), 256, 0, stream>>>(pts, perm, partK);
    knn_merge_kernel<<<64, 256, 0, stream>>>(partK, knn);
    stats_kernel<<<dim3(256, 2), 256, 0, stream>>>(x, knn, w_pe, w_conv, wavept);
    finalize_kernel<<<1, 256, 0, stream>>>(wavept, g_pe, b_pe, g_conv, b_conv, scsh);
    fused_main_kernel<<<1024, 256, 0, stream>>>(x, knn, w_pe, w_conv, w_att1, w_att2,
                                                w_b1, w_b2, scsh, out);
}

// Round 5
// 714.464 us; speedup vs baseline: 1.6013x; 1.6013x over previous
//
#include <hip/hip_runtime.h>
#include <stdint.h>

#define PN 8192
#define SN 8192
#define KNB 16
#define NCHUNK 4
#define CHUNK (PN / NCHUNK)
#define NCHA 8
#define CHA (PN / NCHA)
#define SCAP 36
#define MARGIN 1.0e-3f

#define KEY_SENTINEL ((long long)0x8000000000000000ULL)
#define PD_SCALE 2199023255552.0   // 2^41: dd<1024 -> |scaled|<2^51; <<13 fits i64

// ---------------- kernel 0: pack points (x,y,z,0) ----------------
__global__ void pack_pts_kernel(const float* __restrict__ x, float4* __restrict__ pts) {
    int i = blockIdx.x * 256 + threadIdx.x;           // 0 .. 2*PN-1
    int b = i >> 13, p = i & (PN - 1);
    const float* xb = x + (size_t)b * 4 * PN;
    pts[i] = make_float4(xb[p], xb[PN + p], xb[2 * PN + p], 0.f);
}

// ---------------- kernel 1: stable argsort via bitonic sort of (key,idx) ----------------
__global__ __launch_bounds__(1024) void argsort_kernel(const float* __restrict__ rnd,
                                                       int* __restrict__ perm) {
    __shared__ unsigned long long keys[PN];           // 64 KB
    const int b = blockIdx.x;
    const float* r = rnd + b * PN;
    for (int i = threadIdx.x; i < PN; i += 1024) {
        // rand in [0,1) is non-negative -> raw bits are order-preserving.
        keys[i] = ((unsigned long long)__float_as_uint(r[i]) << 32) | (unsigned)i;
    }
    __syncthreads();
    for (int k = 2; k <= PN; k <<= 1) {
        for (int j = k >> 1; j > 0; j >>= 1) {
            for (int t = threadIdx.x; t < PN; t += 1024) {
                int ixj = t ^ j;
                if (ixj > t) {
                    unsigned long long a = keys[t], c = keys[ixj];
                    bool up = ((t & k) == 0);
                    if ((a > c) == up) { keys[t] = c; keys[ixj] = a; }
                }
            }
            __syncthreads();
        }
    }
    for (int i = threadIdx.x; i < PN; i += 1024)
        perm[b * PN + i] = (int)(keys[i] & 0xffffffffull);
}

// ---------------- kernel 2a: f32 scan -> per-(sample, 1/8-chunk) 16th-smallest dd ----------------
// Cheap f32 value-only top-16 (no indices). Output feeds the exact-refine filter.
__global__ __launch_bounds__(256) void knn_f32_kernel(const float4* __restrict__ pts,
        const int* __restrict__ perm, float* __restrict__ thrv) {
    __shared__ float4 lp[CHA];                        // 16 KB
    const int chunk = blockIdx.x, sg = blockIdx.y, b = blockIdx.z;
    const float4* pb = pts + b * PN;
    const int pbase = chunk * CHA;
    for (int i = threadIdx.x; i < CHA; i += 256) lp[i] = pb[pbase + i];
    __syncthreads();
    const int s = sg * 256 + threadIdx.x;
    const float4 qp = pb[perm[b * PN + s]];
    float v[16];
#pragma unroll
    for (int i = 0; i < 16; ++i) v[i] = 3.0e38f;
    for (int c = 0; c < CHA; ++c) {
        float4 pp = lp[c];
        float dx = qp.x - pp.x, dy = qp.y - pp.y, dz = qp.z - pp.z;
        float dd = dx * dx + dy * dy + dz * dz;
        if (dd < v[15]) {
#pragma unroll
            for (int i = 15; i > 0; --i) {
                bool sh = dd < v[i - 1];
                v[i] = sh ? v[i - 1] : ((dd < v[i]) ? dd : v[i]);
            }
            v[0] = (dd < v[0]) ? dd : v[0];
        }
    }
    thrv[(size_t)(b * NCHA + chunk) * SN + s] = v[15];
}

// ---------------- kernel 2b: filtered exact top-16 per (sample, 1/4-chunk) ----------------
// thr = min(16th of the two half-chunks) + margin  >=  true chunk 16th distance,
// so survivors (<= ~34) contain the whole true top-16; exact f64 keys on survivors only.
__global__ __launch_bounds__(256) void knn_exact_kernel(const float4* __restrict__ pts,
        const int* __restrict__ perm, const float* __restrict__ thrv,
        long long* __restrict__ partK) {
    __shared__ float4 lp[CHUNK];                      // 32 KB
    __shared__ unsigned short surv[256][SCAP];        // 18 KB
    const int chunk = blockIdx.x, sg = blockIdx.y, b = blockIdx.z;
    const float4* pb = pts + b * PN;
    const int pbase = chunk * CHUNK;
    for (int i = threadIdx.x; i < CHUNK; i += 256) lp[i] = pb[pbase + i];
    __syncthreads();
    const int s = sg * 256 + threadIdx.x;
    const float4 qp = pb[perm[b * PN + s]];
    const float t0 = thrv[(size_t)(b * NCHA + 2 * chunk) * SN + s];
    const float t1 = thrv[(size_t)(b * NCHA + 2 * chunk + 1) * SN + s];
    const float thr = fminf(t0, t1) + MARGIN;
    int cnt = 0;
    for (int c = 0; c < CHUNK; ++c) {
        float4 pp = lp[c];
        float dx = qp.x - pp.x, dy = qp.y - pp.y, dz = qp.z - pp.z;
        float dd = dx * dx + dy * dy + dz * dz;
        if (dd <= thr) {
            if (cnt < SCAP) surv[threadIdx.x][cnt] = (unsigned short)c;
            ++cnt;
        }
    }
    if (cnt > SCAP) cnt = SCAP;
    const double qx = qp.x, qy = qp.y, qz = qp.z;
    long long kv[16];
#pragma unroll
    for (int i = 0; i < 16; ++i) kv[i] = KEY_SENTINEL;
    for (int u = 0; u < cnt; ++u) {
        int c = surv[threadIdx.x][u];
        float4 pp = lp[c];
        double dx = qx - (double)pp.x;
        double dy = qy - (double)pp.y;
        double dz = qz - (double)pp.z;
        double dd = dx * dx + dy * dy + dz * dz;
        long long sc = (long long)floor(-dd * PD_SCALE);
        long long kk = (sc << 13) | (long long)(8191 - (pbase + c));
        if (kk > kv[15]) {
#pragma unroll
            for (int i = 15; i > 0; --i) {
                bool sh = kk > kv[i - 1];
                kv[i] = sh ? kv[i - 1] : ((kk > kv[i]) ? kk : kv[i]);
            }
            if (kk > kv[0]) kv[0] = kk;
        }
    }
    long long* ok = partK + ((size_t)(b * NCHUNK + chunk) * SN + s) * KNB;
#pragma unroll
    for (int i = 0; i < KNB; ++i) ok[i] = kv[i];
}

// ---------------- kernel 3: merge 4 sorted chunk-lists, write knn[b][rank][s] ----------------
__global__ void knn_merge_kernel(const long long* __restrict__ partK, int* __restrict__ knn) {
    int t = blockIdx.x * 256 + threadIdx.x;           // 0 .. 2*SN-1
    int b = t >> 13, s = t & (SN - 1);
    const long long* K0 = partK + ((size_t)(b * NCHUNK + 0) * SN + s) * KNB;
    const long long* K1 = partK + ((size_t)(b * NCHUNK + 1) * SN + s) * KNB;
    const long long* K2 = partK + ((size_t)(b * NCHUNK + 2) * SN + s) * KNB;
    const long long* K3 = partK + ((size_t)(b * NCHUNK + 3) * SN + s) * KNB;
    long long h0 = K0[0], h1 = K1[0], h2 = K2[0], h3 = K3[0];
    int p0 = 1, p1 = 1, p2 = 1, p3 = 1;
    int* ob = knn + (size_t)b * (SN * KNB);
    for (int r = 0; r < KNB; ++r) {
        long long m01 = h0 > h1 ? h0 : h1;
        long long m23 = h2 > h3 ? h2 : h3;
        long long m = m01 > m23 ? m01 : m23;
        ob[(size_t)r * SN + s] = 8191 - (int)(m & 8191);
        if (m == h0)      { h0 = (p0 < KNB) ? K0[p0] : KEY_SENTINEL; ++p0; }
        else if (m == h1) { h1 = (p1 < KNB) ? K1[p1] : KEY_SENTINEL; ++p1; }
        else if (m == h2) { h2 = (p2 < KNB) ? K2[p2] : KEY_SENTINEL; ++p2; }
        else              { h3 = (p3 < KNB) ? K3[p3] : KEY_SENTINEL; ++p3; }
    }
}

// ---------------- kernel 4: GroupNorm statistics ----------------
__global__ __launch_bounds__(256) void stats_kernel(const float* __restrict__ x,
        const int* __restrict__ knn, const float* __restrict__ w_pe,
        const float* __restrict__ w_conv, float* __restrict__ wavepart) {
    const int blk = blockIdx.x;                       // 0..255
    const int b = blockIdx.y;
    const int w = threadIdx.x >> 6, l = threadIdx.x & 63;
    float wr[10];
#pragma unroll
    for (int c = 0; c < 10; ++c) wr[c] = 0.f;
    if (l < 32) {
#pragma unroll
        for (int c = 0; c < 4; ++c) wr[c] = w_conv[l * 4 + c];
    } else {
#pragma unroll
        for (int c = 0; c < 10; ++c) wr[c] = w_pe[(l - 32) * 10 + c];
    }
    const float* xb = x + (size_t)b * 4 * PN;
    const int* kb = knn + (size_t)b * (SN * KNB);
    float s1 = 0.f, s2 = 0.f;
    const int nbase = blk * 512 + w * 128;
#pragma unroll 2
    for (int it = 0; it < 128; ++it) {
        int n = nbase + it;
        int i  = kb[n];
        int i0 = kb[n & ~15];
        float xa0 = xb[i], xa1 = xb[PN + i], xa2 = xb[2 * PN + i], xa3 = xb[3 * PN + i];
        float xc0 = xb[i0], xc1 = xb[PN + i0], xc2 = xb[2 * PN + i0];
        float d0 = xa0 - xc0, d1 = xa1 - xc1, d2 = xa2 - xc2;
        float dd = d0 * d0; dd += d1 * d1; dd += d2 * d2;
        float temp = sqrtf(fmaxf(dd, 1e-12f));
        float r;
        if (l < 32) {
            r = wr[0] * xa0 + wr[1] * xa1 + wr[2] * xa2 + wr[3] * xa3;
        } else {
            r = wr[0] * xa0 + wr[1] * xa1 + wr[2] * xa2
              + wr[3] * xc0 + wr[4] * xc1 + wr[5] * xc2
              + wr[6] * d0 + wr[7] * d1 + wr[8] * d2 + wr[9] * temp;
        }
        s1 += r;
        s2 += r * r;
    }
    const int wslot = blk * 4 + w;                    // 0..1023
    wavepart[((size_t)b * 1024 + wslot) * 128 + l] = s1;
    wavepart[((size_t)b * 1024 + wslot) * 128 + 64 + l] = s2;
}

// ---------------- kernel 5: finalize stats -> per-channel scale/shift ----------------
__global__ void finalize_kernel(const float* __restrict__ wavepart,
        const float* __restrict__ g_pe, const float* __restrict__ b_pe,
        const float* __restrict__ g_conv, const float* __restrict__ b_conv,
        float* __restrict__ scsh) {
    const int t = threadIdx.x;                        // 0..255
    const int b = t >> 7, k = t & 127;
    float acc = 0.f;
    for (int w = 0; w < 1024; ++w) acc += wavepart[((size_t)b * 1024 + w) * 128 + k];
    __shared__ float sums[2][128];
    sums[b][k] = acc;
    __syncthreads();
    if (k < 64) {
        const float N = 131072.f;
        float mean = sums[b][k] / N;
        float var = sums[b][64 + k] / N - mean * mean;
        float rstd = 1.0f / sqrtf(var + 1e-5f);
        float gam = (k < 32) ? g_conv[k] : g_pe[k - 32];
        float bet = (k < 32) ? b_conv[k] : b_pe[k - 32];
        float sc = gam * rstd;
        scsh[(b * 64 + k) * 2 + 0] = sc;
        scsh[(b * 64 + k) * 2 + 1] = bet - mean * sc;
    }
}

// ---------------- kernel 6: fused feature/attention/output ----------------
__global__ __launch_bounds__(256) void fused_main_kernel(
        const float* __restrict__ x, const int* __restrict__ knn,
        const float* __restrict__ w_pe, const float* __restrict__ w_conv,
        const float* __restrict__ w_att1, const float* __restrict__ w_att2,
        const float* __restrict__ w_b1, const float* __restrict__ w_b2,
        const float* __restrict__ scsh, float* __restrict__ out) {
    __shared__ float wb1T[64 * 64];                   // [c][o]
    __shared__ float wb2T[4 * 64];                    // [c][o]
    for (int i = threadIdx.x; i < 64 * 64; i += 256) wb1T[(i & 63) * 64 + (i >> 6)] = w_b1[i];
    { int i = threadIdx.x; wb2T[(i & 3) * 64 + (i >> 2)] = w_b2[i]; }
    __syncthreads();
    const int gidx = blockIdx.x;                      // 0..1023
    const int b = gidx >> 9;
    const int sb = (gidx & 511) << 4;
    const int l = threadIdx.x & 63;
    const int w = threadIdx.x >> 6;
    const int g = l >> 4, j = l & 15;
    const int s = sb + (w << 2) + g;
    const int srcl = g << 4;
    const float* xb = x + (size_t)b * 4 * PN;
    const int i1 = knn[(size_t)b * (SN * KNB) + (size_t)s * KNB + j];
    float xa0 = xb[i1], xa1 = xb[PN + i1], xa2 = xb[2 * PN + i1], xa3 = xb[3 * PN + i1];
    float xc0 = __shfl(xa0, srcl), xc1 = __shfl(xa1, srcl);
    float xc2 = __shfl(xa2, srcl), xc3 = __shfl(xa3, srcl);
    float d0 = xa0 - xc0, d1 = xa1 - xc1, d2 = xa2 - xc2;
    float dd = d0 * d0; dd += d1 * d1; dd += d2 * d2;
    float temp = sqrtf(fmaxf(dd, 1e-12f));
    float pem[10] = {xa0, xa1, xa2, xc0, xc1, xc2, d0, d1, d2, temp};
    float f[64];
    const float* ssb = scsh + b * 128;
#pragma unroll
    for (int o = 0; o < 32; ++o) {
        float r = w_conv[o * 4 + 0] * xa0;
        r += w_conv[o * 4 + 1] * xa1;
        r += w_conv[o * 4 + 2] * xa2;
        r += w_conv[o * 4 + 3] * xa3;
        r = r * ssb[o * 2 + 0] + ssb[o * 2 + 1];
        f[o] = (r >= 0.f) ? r : 0.2f * r;
    }
#pragma unroll
    for (int o = 0; o < 32; ++o) {
        float r = 0.f;
#pragma unroll
        for (int c = 0; c < 10; ++c) r += w_pe[o * 10 + c] * pem[c];
        r = r * ssb[(32 + o) * 2 + 0] + ssb[(32 + o) * 2 + 1];
        f[32 + o] = (r >= 0.f) ? r : 0.2f * r;
    }
    float logit = 0.f;
#pragma unroll 2
    for (int o = 0; o < 32; ++o) {
        float a = 0.f;
#pragma unroll
        for (int c = 0; c < 64; ++c) a += w_att1[o * 64 + c] * f[c];
        a = (a >= 0.f) ? a : 0.2f * a;
        logit += w_att2[o] * a;
    }
    float mx = logit;
    mx = fmaxf(mx, __shfl_xor(mx, 1));
    mx = fmaxf(mx, __shfl_xor(mx, 2));
    mx = fmaxf(mx, __shfl_xor(mx, 4));
    mx = fmaxf(mx, __shfl_xor(mx, 8));
    float e = expf(logit - mx);
    float se = e;
    se += __shfl_xor(se, 1);
    se += __shfl_xor(se, 2);
    se += __shfl_xor(se, 4);
    se += __shfl_xor(se, 8);
    float att = e / se;
#pragma unroll
    for (int c = 0; c < 64; ++c) {
        float v = f[c] * att;
        v += __shfl_xor(v, 1);
        v += __shfl_xor(v, 2);
        v += __shfl_xor(v, 4);
        v += __shfl_xor(v, 8);
        f[c] = v;
    }
    float o0 = 0.f, o1 = 0.f, o2 = 0.f, o3 = 0.f;
#pragma unroll
    for (int c = 0; c < 64; ++c) {
        float4 wv = *reinterpret_cast<const float4*>(&wb1T[c * 64 + 4 * j]);
        o0 += wv.x * f[c]; o1 += wv.y * f[c]; o2 += wv.z * f[c]; o3 += wv.w * f[c];
    }
    {
        float4 wv = *reinterpret_cast<const float4*>(&wb2T[0 * 64 + 4 * j]);
        o0 += wv.x * xc0; o1 += wv.y * xc0; o2 += wv.z * xc0; o3 += wv.w * xc0;
        wv = *reinterpret_cast<const float4*>(&wb2T[1 * 64 + 4 * j]);
        o0 += wv.x * xc1; o1 += wv.y * xc1; o2 += wv.z * xc1; o3 += wv.w * xc1;
        wv = *reinterpret_cast<const float4*>(&wb2T[2 * 64 + 4 * j]);
        o0 += wv.x * xc2; o1 += wv.y * xc2; o2 += wv.z * xc2; o3 += wv.w * xc2;
        wv = *reinterpret_cast<const float4*>(&wb2T[3 * 64 + 4 * j]);
        o0 += wv.x * xc3; o1 += wv.y * xc3; o2 += wv.z * xc3; o3 += wv.w * xc3;
    }
    o0 = (o0 >= 0.f) ? o0 : 0.1f * o0;
    o1 = (o1 >= 0.f) ? o1 : 0.1f * o1;
    o2 = (o2 >= 0.f) ? o2 : 0.1f * o2;
    o3 = (o3 >= 0.f) ? o3 : 0.1f * o3;
    float* ob = out + (size_t)b * 67 * SN;
    const int oc = 3 + 4 * j;
    ob[(size_t)(oc + 0) * SN + s] = o0;
    ob[(size_t)(oc + 1) * SN + s] = o1;
    ob[(size_t)(oc + 2) * SN + s] = o2;
    ob[(size_t)(oc + 3) * SN + s] = o3;
    if (j < 3) ob[(size_t)j * SN + s] = (j == 0) ? xc0 : ((j == 1) ? xc1 : xc2);
}

extern "C" void kernel_launch(void* const* d_in, const int* in_sizes, int n_in,
                              void* d_out, int out_size, void* d_ws, size_t ws_size,
                              hipStream_t stream) {
    (void)in_sizes; (void)n_in; (void)out_size; (void)ws_size;
    const float* x      = (const float*)d_in[0];
    const float* rnd    = (const float*)d_in[1];
    const float* w_pe   = (const float*)d_in[2];
    const float* g_pe   = (const float*)d_in[3];
    const float* b_pe   = (const float*)d_in[4];
    const float* w_conv = (const float*)d_in[5];
    const float* g_conv = (const float*)d_in[6];
    const float* b_conv = (const float*)d_in[7];
    const float* w_att1 = (const float*)d_in[8];
    const float* w_att2 = (const float*)d_in[9];
    const float* w_b1   = (const float*)d_in[10];
    const float* w_b2   = (const float*)d_in[11];
    float* out = (float*)d_out;
    char* ws = (char*)d_ws;
    // workspace carve-up (bytes), total ~10.8 MB (unchanged footprint).
    // thrv (512 KB) aliases wavept: dead once knn_exact completes, before stats runs.
    float4*    pts    = (float4*)   (ws + 0);         //   262,144
    int*       perm   = (int*)      (ws + 262144);    //    65,536
    long long* partK  = (long long*)(ws + 327680);    // 8,388,608
    int*       knn    = (int*)      (ws + 8716288);   // 1,048,576
    float*     wavept = (float*)    (ws + 9764864);   // 1,048,576
    float*     thrv   = (float*)    (ws + 9764864);   //   524,288 (alias, dead before stats)
    float*     scsh   = (float*)    (ws + 10813440);  //     1,024

    pack_pts_kernel<<<64, 256, 0, stream>>>(x, pts);
    argsort_kernel<<<2, 1024, 0, stream>>>(rnd, perm);
    knn_f32_kernel<<<dim3(NCHA, 32, 2), 256, 0, stream>>>(pts, perm, thrv);
    knn_exact_kernel<<<dim3(NCHUNK, 32, 2), 256, 0, stream>>>(pts, perm, thrv, partK);
    knn_merge_kernel<<<64, 256, 0, stream>>>(partK, knn);
    stats_kernel<<<dim3(256, 2), 256, 0, stream>>>(x, knn, w_pe, w_conv, wavept);
    finalize_kernel<<<1, 256, 0, stream>>>(wavept, g_pe, b_pe, g_conv, b_conv, scsh);
    fused_main_kernel<<<1024, 256, 0, stream>>>(x, knn, w_pe, w_conv, w_att1, w_att2,
                                                w_b1, w_b2, scsh, out);
}

// Round 6
// 685.714 us; speedup vs baseline: 1.6685x; 1.0419x over previous
//
#include <hip/hip_runtime.h>
#include <stdint.h>

#define PN 8192
#define SN 8192
#define KNB 16
#define NCHUNK 4
#define CHUNK (PN / NCHUNK)
#define SCAP 128

#define KEY_SENTINEL ((long long)0x8000000000000000ULL)
#define PD_SCALE 2199023255552.0   // 2^41: dd<1024 -> |scaled|<2^51; <<13 fits i64

// dd-threshold ladder: 2^(k-6), k=0..14. Covers [0.0156, 256]; max pairwise dd ~243.
__device__ __constant__ float TAU[15] = {
    0.015625f, 0.03125f, 0.0625f, 0.125f, 0.25f, 0.5f, 1.0f, 2.0f,
    4.0f, 8.0f, 16.0f, 32.0f, 64.0f, 128.0f, 256.0f};

// ---------------- kernel 0: pack points (x,y,z,0) ----------------
__global__ void pack_pts_kernel(const float* __restrict__ x, float4* __restrict__ pts) {
    int i = blockIdx.x * 256 + threadIdx.x;           // 0 .. 2*PN-1
    int b = i >> 13, p = i & (PN - 1);
    const float* xb = x + (size_t)b * 4 * PN;
    pts[i] = make_float4(xb[p], xb[PN + p], xb[2 * PN + p], 0.f);
}

// ---------------- kernel 1: stable argsort via bitonic sort of (key,idx) ----------------
__global__ __launch_bounds__(1024) void argsort_kernel(const float* __restrict__ rnd,
                                                       int* __restrict__ perm) {
    __shared__ unsigned long long keys[PN];           // 64 KB
    const int b = blockIdx.x;
    const float* r = rnd + b * PN;
    for (int i = threadIdx.x; i < PN; i += 1024) {
        // rand in [0,1) is non-negative -> raw bits are order-preserving.
        keys[i] = ((unsigned long long)__float_as_uint(r[i]) << 32) | (unsigned)i;
    }
    __syncthreads();
    for (int k = 2; k <= PN; k <<= 1) {
        for (int j = k >> 1; j > 0; j >>= 1) {
            for (int t = threadIdx.x; t < PN; t += 1024) {
                int ixj = t ^ j;
                if (ixj > t) {
                    unsigned long long a = keys[t], c = keys[ixj];
                    bool up = ((t & k) == 0);
                    if ((a > c) == up) { keys[t] = c; keys[ixj] = a; }
                }
            }
            __syncthreads();
        }
    }
    for (int i = threadIdx.x; i < PN; i += 1024)
        perm[b * PN + i] = (int)(keys[i] & 0xffffffffull);
}

// ---------------- kernel 2: fused count / filter / exact top-16 per (sample, chunk) ----------
// Phase 1: branch-free ladder counting -> per-thread threshold thr >= chunk's true 16th dd.
// Phase 2: collect survivor indices (dd < thr), ~45 expected, cap 128 (P(overflow)<1e-15).
// Phase 3: exact f64 distance keys on survivors only -> true chunk top-16, exact tie order.
__global__ __launch_bounds__(256) void knn_chunk_kernel(const float4* __restrict__ pts,
        const int* __restrict__ perm, long long* __restrict__ partK) {
    __shared__ float4 lp[CHUNK];                      // 32 KB
    __shared__ unsigned short surv[SCAP][256];        // 64 KB ([u][tid]: bank-spread reads)
    const int chunk = blockIdx.x, sg = blockIdx.y, b = blockIdx.z;
    const float4* pb = pts + b * PN;
    const int pbase = chunk * CHUNK;
    for (int i = threadIdx.x; i < CHUNK; i += 256) lp[i] = pb[pbase + i];
    __syncthreads();
    const int s = sg * 256 + threadIdx.x;
    const float4 qp = pb[perm[b * PN + s]];

    // ---- phase 1: count dd < TAU[k] for all k (no branches, no serial chains) ----
    int cn[15];
#pragma unroll
    for (int k = 0; k < 15; ++k) cn[k] = 0;
#pragma unroll 4
    for (int c = 0; c < CHUNK; ++c) {
        float4 pp = lp[c];
        float dx = qp.x - pp.x, dy = qp.y - pp.y, dz = qp.z - pp.z;
        float dd = dx * dx + dy * dy + dz * dz;
#pragma unroll
        for (int k = 0; k < 15; ++k) cn[k] += (dd < TAU[k]) ? 1 : 0;
    }
    float thr = 3.0e38f;
#pragma unroll
    for (int k = 14; k >= 0; --k) if (cn[k] >= 16) thr = TAU[k];
    thr *= 1.000004f;   // absorb any FMA-contraction difference vs phase-2 dd

    // ---- phase 2: collect survivors ----
    int cnt = 0;
#pragma unroll 4
    for (int c = 0; c < CHUNK; ++c) {
        float4 pp = lp[c];
        float dx = qp.x - pp.x, dy = qp.y - pp.y, dz = qp.z - pp.z;
        float dd = dx * dx + dy * dy + dz * dz;
        if (dd < thr) {
            if (cnt < SCAP) surv[cnt][threadIdx.x] = (unsigned short)c;
            ++cnt;
        }
    }
    if (cnt > SCAP) cnt = SCAP;

    // ---- phase 3: exact top-16 among survivors (f64 keys, index tie-break) ----
    const double qx = qp.x, qy = qp.y, qz = qp.z;
    long long kv[16];
#pragma unroll
    for (int i = 0; i < 16; ++i) kv[i] = KEY_SENTINEL;
    for (int u = 0; u < cnt; ++u) {
        int c = surv[u][threadIdx.x];
        float4 pp = lp[c];
        double dx = qx - (double)pp.x;
        double dy = qy - (double)pp.y;
        double dz = qz - (double)pp.z;
        double dd = dx * dx + dy * dy + dz * dz;
        long long sc = (long long)floor(-dd * PD_SCALE);
        long long kk = (sc << 13) | (long long)(8191 - (pbase + c));
        if (kk > kv[15]) {
#pragma unroll
            for (int i = 15; i > 0; --i) {
                bool sh = kk > kv[i - 1];
                kv[i] = sh ? kv[i - 1] : ((kk > kv[i]) ? kk : kv[i]);
            }
            if (kk > kv[0]) kv[0] = kk;
        }
    }
    long long* ok = partK + ((size_t)(b * NCHUNK + chunk) * SN + s) * KNB;
#pragma unroll
    for (int i = 0; i < KNB; ++i) ok[i] = kv[i];
}

// ---------------- kernel 3: merge 4 sorted chunk-lists, write knn[b][rank][s] ----------------
__global__ void knn_merge_kernel(const long long* __restrict__ partK, int* __restrict__ knn) {
    int t = blockIdx.x * 256 + threadIdx.x;           // 0 .. 2*SN-1
    int b = t >> 13, s = t & (SN - 1);
    const long long* K0 = partK + ((size_t)(b * NCHUNK + 0) * SN + s) * KNB;
    const long long* K1 = partK + ((size_t)(b * NCHUNK + 1) * SN + s) * KNB;
    const long long* K2 = partK + ((size_t)(b * NCHUNK + 2) * SN + s) * KNB;
    const long long* K3 = partK + ((size_t)(b * NCHUNK + 3) * SN + s) * KNB;
    long long h0 = K0[0], h1 = K1[0], h2 = K2[0], h3 = K3[0];
    int p0 = 1, p1 = 1, p2 = 1, p3 = 1;
    int* ob = knn + (size_t)b * (SN * KNB);
    for (int r = 0; r < KNB; ++r) {
        long long m01 = h0 > h1 ? h0 : h1;
        long long m23 = h2 > h3 ? h2 : h3;
        long long m = m01 > m23 ? m01 : m23;
        ob[(size_t)r * SN + s] = 8191 - (int)(m & 8191);
        if (m == h0)      { h0 = (p0 < KNB) ? K0[p0] : KEY_SENTINEL; ++p0; }
        else if (m == h1) { h1 = (p1 < KNB) ? K1[p1] : KEY_SENTINEL; ++p1; }
        else if (m == h2) { h2 = (p2 < KNB) ? K2[p2] : KEY_SENTINEL; ++p2; }
        else              { h3 = (p3 < KNB) ? K3[p3] : KEY_SENTINEL; ++p3; }
    }
}

// ---------------- kernel 4: GroupNorm statistics ----------------
__global__ __launch_bounds__(256) void stats_kernel(const float* __restrict__ x,
        const int* __restrict__ knn, const float* __restrict__ w_pe,
        const float* __restrict__ w_conv, float* __restrict__ wavepart) {
    const int blk = blockIdx.x;                       // 0..255
    const int b = blockIdx.y;
    const int w = threadIdx.x >> 6, l = threadIdx.x & 63;
    float wr[10];
#pragma unroll
    for (int c = 0; c < 10; ++c) wr[c] = 0.f;
    if (l < 32) {
#pragma unroll
        for (int c = 0; c < 4; ++c) wr[c] = w_conv[l * 4 + c];
    } else {
#pragma unroll
        for (int c = 0; c < 10; ++c) wr[c] = w_pe[(l - 32) * 10 + c];
    }
    const float* xb = x + (size_t)b * 4 * PN;
    const int* kb = knn + (size_t)b * (SN * KNB);
    float s1 = 0.f, s2 = 0.f;
    const int nbase = blk * 512 + w * 128;
#pragma unroll 2
    for (int it = 0; it < 128; ++it) {
        int n = nbase + it;
        int i  = kb[n];
        int i0 = kb[n & ~15];
        float xa0 = xb[i], xa1 = xb[PN + i], xa2 = xb[2 * PN + i], xa3 = xb[3 * PN + i];
        float xc0 = xb[i0], xc1 = xb[PN + i0], xc2 = xb[2 * PN + i0];
        float d0 = xa0 - xc0, d1 = xa1 - xc1, d2 = xa2 - xc2;
        float dd = d0 * d0; dd += d1 * d1; dd += d2 * d2;
        float temp = sqrtf(fmaxf(dd, 1e-12f));
        float r;
        if (l < 32) {
            r = wr[0] * xa0 + wr[1] * xa1 + wr[2] * xa2 + wr[3] * xa3;
        } else {
            r = wr[0] * xa0 + wr[1] * xa1 + wr[2] * xa2
              + wr[3] * xc0 + wr[4] * xc1 + wr[5] * xc2
              + wr[6] * d0 + wr[7] * d1 + wr[8] * d2 + wr[9] * temp;
        }
        s1 += r;
        s2 += r * r;
    }
    const int wslot = blk * 4 + w;                    // 0..1023
    wavepart[((size_t)b * 1024 + wslot) * 128 + l] = s1;
    wavepart[((size_t)b * 1024 + wslot) * 128 + 64 + l] = s2;
}

// ---------------- kernel 5: finalize stats -> per-channel scale/shift ----------------
__global__ void finalize_kernel(const float* __restrict__ wavepart,
        const float* __restrict__ g_pe, const float* __restrict__ b_pe,
        const float* __restrict__ g_conv, const float* __restrict__ b_conv,
        float* __restrict__ scsh) {
    const int t = threadIdx.x;                        // 0..255
    const int b = t >> 7, k = t & 127;
    float acc = 0.f;
    for (int w = 0; w < 1024; ++w) acc += wavepart[((size_t)b * 1024 + w) * 128 + k];
    __shared__ float sums[2][128];
    sums[b][k] = acc;
    __syncthreads();
    if (k < 64) {
        const float N = 131072.f;
        float mean = sums[b][k] / N;
        float var = sums[b][64 + k] / N - mean * mean;
        float rstd = 1.0f / sqrtf(var + 1e-5f);
        float gam = (k < 32) ? g_conv[k] : g_pe[k - 32];
        float bet = (k < 32) ? b_conv[k] : b_pe[k - 32];
        float sc = gam * rstd;
        scsh[(b * 64 + k) * 2 + 0] = sc;
        scsh[(b * 64 + k) * 2 + 1] = bet - mean * sc;
    }
}

// ---------------- kernel 6: fused feature/attention/output ----------------
__global__ __launch_bounds__(256) void fused_main_kernel(
        const float* __restrict__ x, const int* __restrict__ knn,
        const float* __restrict__ w_pe, const float* __restrict__ w_conv,
        const float* __restrict__ w_att1, const float* __restrict__ w_att2,
        const float* __restrict__ w_b1, const float* __restrict__ w_b2,
        const float* __restrict__ scsh, float* __restrict__ out) {
    __shared__ float wb1T[64 * 64];                   // [c][o]
    __shared__ float wb2T[4 * 64];                    // [c][o]
    for (int i = threadIdx.x; i < 64 * 64; i += 256) wb1T[(i & 63) * 64 + (i >> 6)] = w_b1[i];
    { int i = threadIdx.x; wb2T[(i & 3) * 64 + (i >> 2)] = w_b2[i]; }
    __syncthreads();
    const int gidx = blockIdx.x;                      // 0..1023
    const int b = gidx >> 9;
    const int sb = (gidx & 511) << 4;
    const int l = threadIdx.x & 63;
    const int w = threadIdx.x >> 6;
    const int g = l >> 4, j = l & 15;
    const int s = sb + (w << 2) + g;
    const int srcl = g << 4;
    const float* xb = x + (size_t)b * 4 * PN;
    const int i1 = knn[(size_t)b * (SN * KNB) + (size_t)s * KNB + j];
    float xa0 = xb[i1], xa1 = xb[PN + i1], xa2 = xb[2 * PN + i1], xa3 = xb[3 * PN + i1];
    float xc0 = __shfl(xa0, srcl), xc1 = __shfl(xa1, srcl);
    float xc2 = __shfl(xa2, srcl), xc3 = __shfl(xa3, srcl);
    float d0 = xa0 - xc0, d1 = xa1 - xc1, d2 = xa2 - xc2;
    float dd = d0 * d0; dd += d1 * d1; dd += d2 * d2;
    float temp = sqrtf(fmaxf(dd, 1e-12f));
    float pem[10] = {xa0, xa1, xa2, xc0, xc1, xc2, d0, d1, d2, temp};
    float f[64];
    const float* ssb = scsh + b * 128;
#pragma unroll
    for (int o = 0; o < 32; ++o) {
        float r = w_conv[o * 4 + 0] * xa0;
        r += w_conv[o * 4 + 1] * xa1;
        r += w_conv[o * 4 + 2] * xa2;
        r += w_conv[o * 4 + 3] * xa3;
        r = r * ssb[o * 2 + 0] + ssb[o * 2 + 1];
        f[o] = (r >= 0.f) ? r : 0.2f * r;
    }
#pragma unroll
    for (int o = 0; o < 32; ++o) {
        float r = 0.f;
#pragma unroll
        for (int c = 0; c < 10; ++c) r += w_pe[o * 10 + c] * pem[c];
        r = r * ssb[(32 + o) * 2 + 0] + ssb[(32 + o) * 2 + 1];
        f[32 + o] = (r >= 0.f) ? r : 0.2f * r;
    }
    float logit = 0.f;
#pragma unroll 2
    for (int o = 0; o < 32; ++o) {
        float a = 0.f;
#pragma unroll
        for (int c = 0; c < 64; ++c) a += w_att1[o * 64 + c] * f[c];
        a = (a >= 0.f) ? a : 0.2f * a;
        logit += w_att2[o] * a;
    }
    float mx = logit;
    mx = fmaxf(mx, __shfl_xor(mx, 1));
    mx = fmaxf(mx, __shfl_xor(mx, 2));
    mx = fmaxf(mx, __shfl_xor(mx, 4));
    mx = fmaxf(mx, __shfl_xor(mx, 8));
    float e = expf(logit - mx);
    float se = e;
    se += __shfl_xor(se, 1);
    se += __shfl_xor(se, 2);
    se += __shfl_xor(se, 4);
    se += __shfl_xor(se, 8);
    float att = e / se;
#pragma unroll
    for (int c = 0; c < 64; ++c) {
        float v = f[c] * att;
        v += __shfl_xor(v, 1);
        v += __shfl_xor(v, 2);
        v += __shfl_xor(v, 4);
        v += __shfl_xor(v, 8);
        f[c] = v;
    }
    float o0 = 0.f, o1 = 0.f, o2 = 0.f, o3 = 0.f;
#pragma unroll
    for (int c = 0; c < 64; ++c) {
        float4 wv = *reinterpret_cast<const float4*>(&wb1T[c * 64 + 4 * j]);
        o0 += wv.x * f[c]; o1 += wv.y * f[c]; o2 += wv.z * f[c]; o3 += wv.w * f[c];
    }
    {
        float4 wv = *reinterpret_cast<const float4*>(&wb2T[0 * 64 + 4 * j]);
        o0 += wv.x * xc0; o1 += wv.y * xc0; o2 += wv.z * xc0; o3 += wv.w * xc0;
        wv = *reinterpret_cast<const float4*>(&wb2T[1 * 64 + 4 * j]);
        o0 += wv.x * xc1; o1 += wv.y * xc1; o2 += wv.z * xc1; o3 += wv.w * xc1;
        wv = *reinterpret_cast<const float4*>(&wb2T[2 * 64 + 4 * j]);
        o0 += wv.x * xc2; o1 += wv.y * xc2; o2 += wv.z * xc2; o3 += wv.w * xc2;
        wv = *reinterpret_cast<const float4*>(&wb2T[3 * 64 + 4 * j]);
        o0 += wv.x * xc3; o1 += wv.y * xc3; o2 += wv.z * xc3; o3 += wv.w * xc3;
    }
    o0 = (o0 >= 0.f) ? o0 : 0.1f * o0;
    o1 = (o1 >= 0.f) ? o1 : 0.1f * o1;
    o2 = (o2 >= 0.f) ? o2 : 0.1f * o2;
    o3 = (o3 >= 0.f) ? o3 : 0.1f * o3;
    float* ob = out + (size_t)b * 67 * SN;
    const int oc = 3 + 4 * j;
    ob[(size_t)(oc + 0) * SN + s] = o0;
    ob[(size_t)(oc + 1) * SN + s] = o1;
    ob[(size_t)(oc + 2) * SN + s] = o2;
    ob[(size_t)(oc + 3) * SN + s] = o3;
    if (j < 3) ob[(size_t)j * SN + s] = (j == 0) ? xc0 : ((j == 1) ? xc1 : xc2);
}

extern "C" void kernel_launch(void* const* d_in, const int* in_sizes, int n_in,
                              void* d_out, int out_size, void* d_ws, size_t ws_size,
                              hipStream_t stream) {
    (void)in_sizes; (void)n_in; (void)out_size; (void)ws_size;
    const float* x      = (const float*)d_in[0];
    const float* rnd    = (const float*)d_in[1];
    const float* w_pe   = (const float*)d_in[2];
    const float* g_pe   = (const float*)d_in[3];
    const float* b_pe   = (const float*)d_in[4];
    const float* w_conv = (const float*)d_in[5];
    const float* g_conv = (const float*)d_in[6];
    const float* b_conv = (const float*)d_in[7];
    const float* w_att1 = (const float*)d_in[8];
    const float* w_att2 = (const float*)d_in[9];
    const float* w_b1   = (const float*)d_in[10];
    const float* w_b2   = (const float*)d_in[11];
    float* out = (float*)d_out;
    char* ws = (char*)d_ws;
    // workspace carve-up (bytes), total ~10.8 MB (unchanged footprint)
    float4*    pts    = (float4*)   (ws + 0);         //   262,144
    int*       perm   = (int*)      (ws + 262144);    //    65,536
    long long* partK  = (long long*)(ws + 327680);    // 8,388,608
    int*       knn    = (int*)      (ws + 8716288);   // 1,048,576
    float*     wavept = (float*)    (ws + 9764864);   // 1,048,576
    float*     scsh   = (float*)    (ws + 10813440);  //     1,024

    pack_pts_kernel<<<64, 256, 0, stream>>>(x, pts);
    argsort_kernel<<<2, 1024, 0, stream>>>(rnd, perm);
    knn_chunk_kernel<<<dim3(NCHUNK, 32, 2), 256, 0, stream>>>(pts, perm, partK);
    knn_merge_kernel<<<64, 256, 0, stream>>>(partK, knn);
    stats_kernel<<<dim3(256, 2), 256, 0, stream>>>(x, knn, w_pe, w_conv, wavept);
    finalize_kernel<<<1, 256, 0, stream>>>(wavept, g_pe, b_pe, g_conv, b_conv, scsh);
    fused_main_kernel<<<1024, 256, 0, stream>>>(x, knn, w_pe, w_conv, w_att1, w_att2,
                                                w_b1, w_b2, scsh, out);
}

// Round 7
// 430.397 us; speedup vs baseline: 2.6582x; 1.5932x over previous
//
#include <hip/hip_runtime.h>
#include <stdint.h>

#define PN 8192
#define SN 8192
#define KNB 16
#define NCH1 8
#define CHUNK1 (PN / NCH1)    // 1024
#define NCH2 16
#define CHUNK2 (PN / NCH2)    // 512
#define SCAP 48
#define MARGIN 1.0e-3f

#define KEY_SENTINEL ((long long)0x8000000000000000ULL)
#define PD_SCALE 2199023255552.0   // 2^41: dd<1024 -> |scaled|<2^51; <<13 fits i64

// ---------------- helpers: branch-free sorted-16 maintenance ----------------
__device__ __forceinline__ void bitonic_sort16(float* b) {
#pragma unroll
    for (int k = 2; k <= 16; k <<= 1) {
#pragma unroll
        for (int j = k >> 1; j > 0; j >>= 1) {
#pragma unroll
            for (int i = 0; i < 16; ++i) {
                int l = i ^ j;
                if (l > i) {
                    float lo = fminf(b[i], b[l]), hi = fmaxf(b[i], b[l]);
                    bool up = ((i & k) == 0);
                    b[i] = up ? lo : hi;
                    b[l] = up ? hi : lo;
                }
            }
        }
    }
}
// r, b ascending sorted-16 -> r = lowest 16 of union, ascending.
__device__ __forceinline__ void merge16(float* r, const float* b) {
    float t[16];
#pragma unroll
    for (int i = 0; i < 16; ++i) t[i] = fminf(r[i], b[15 - i]);   // bitonic
#pragma unroll
    for (int j = 8; j > 0; j >>= 1) {
#pragma unroll
        for (int i = 0; i < 16; ++i) {
            int l = i ^ j;
            if (l > i) {
                float lo = fminf(t[i], t[l]), hi = fmaxf(t[i], t[l]);
                t[i] = lo; t[l] = hi;
            }
        }
    }
#pragma unroll
    for (int i = 0; i < 16; ++i) r[i] = t[i];
}

// ---------------- kernel 0: pack points (x,y,z,0) ----------------
__global__ void pack_pts_kernel(const float* __restrict__ x, float4* __restrict__ pts) {
    int i = blockIdx.x * 256 + threadIdx.x;           // 0 .. 2*PN-1
    int b = i >> 13, p = i & (PN - 1);
    const float* xb = x + (size_t)b * 4 * PN;
    pts[i] = make_float4(xb[p], xb[PN + p], xb[2 * PN + p], 0.f);
}

// ---------------- kernel 1: stable argsort via bitonic sort of (key,idx) ----------------
__global__ __launch_bounds__(1024) void argsort_kernel(const float* __restrict__ rnd,
                                                       int* __restrict__ perm) {
    __shared__ unsigned long long keys[PN];           // 64 KB
    const int b = blockIdx.x;
    const float* r = rnd + b * PN;
    for (int i = threadIdx.x; i < PN; i += 1024) {
        // rand in [0,1) is non-negative -> raw bits are order-preserving.
        keys[i] = ((unsigned long long)__float_as_uint(r[i]) << 32) | (unsigned)i;
    }
    __syncthreads();
    for (int k = 2; k <= PN; k <<= 1) {
        for (int j = k >> 1; j > 0; j >>= 1) {
            for (int t = threadIdx.x; t < PN; t += 1024) {
                int ixj = t ^ j;
                if (ixj > t) {
                    unsigned long long a = keys[t], c = keys[ixj];
                    bool up = ((t & k) == 0);
                    if ((a > c) == up) { keys[t] = c; keys[ixj] = a; }
                }
            }
            __syncthreads();
        }
    }
    for (int i = threadIdx.x; i < PN; i += 1024)
        perm[b * PN + i] = (int)(keys[i] & 0xffffffffull);
}

// ---------------- K1: per-(sample, 1/8-chunk) sorted f32 top-16 distances ----------------
// Batch-16 sorting network; zero branches, zero LDS conflicts (broadcast reads).
__global__ __launch_bounds__(256) void knn_val16_kernel(const float4* __restrict__ pts,
        const int* __restrict__ perm, float* __restrict__ vv) {
    __shared__ float4 lp[CHUNK1];                     // 16 KB
    const int chunk = blockIdx.x, sg = blockIdx.y, b = blockIdx.z;
    const float4* pb = pts + b * PN;
    const int pbase = chunk * CHUNK1;
    for (int i = threadIdx.x; i < CHUNK1; i += 256) lp[i] = pb[pbase + i];
    __syncthreads();
    const int s = sg * 256 + threadIdx.x;
    const float4 qp = pb[perm[b * PN + s]];
    float r[16];
#pragma unroll
    for (int i = 0; i < 16; ++i) r[i] = 3.0e38f;
    for (int t = 0; t < CHUNK1; t += 16) {
        float bv[16];
#pragma unroll
        for (int u = 0; u < 16; ++u) {
            float4 pp = lp[t + u];
            float dx = qp.x - pp.x, dy = qp.y - pp.y, dz = qp.z - pp.z;
            bv[u] = dx * dx + dy * dy + dz * dz;
        }
        bitonic_sort16(bv);
        merge16(r, bv);
    }
    float* ov = vv + ((size_t)(b * NCH1 + chunk) * 16) * SN + s;
#pragma unroll
    for (int i = 0; i < 16; ++i) ov[(size_t)i * SN] = r[i];
}

// ---------------- K1.5: merge 8 sorted chunk value-lists -> global v15 -> thr ----------------
__global__ void knn_thr_kernel(const float* __restrict__ vv, float* __restrict__ thrbuf) {
    int t = blockIdx.x * 256 + threadIdx.x;           // 0 .. 2*SN-1
    int b = t >> 13, s = t & (SN - 1);
    float r[16], bl[16];
    const float* v0 = vv + ((size_t)(b * NCH1) * 16) * SN + s;
#pragma unroll
    for (int i = 0; i < 16; ++i) r[i] = v0[(size_t)i * SN];
    for (int ch = 1; ch < NCH1; ++ch) {
        const float* vc = vv + ((size_t)(b * NCH1 + ch) * 16) * SN + s;
#pragma unroll
        for (int i = 0; i < 16; ++i) bl[i] = vc[(size_t)i * SN];
        merge16(r, bl);
    }
    thrbuf[b * SN + s] = r[15] + MARGIN;              // >= true global d16 (superset proof)
}

// ---------------- K2: collect survivors (dd < thr) into global per-sample lists ----------------
__global__ __launch_bounds__(256) void knn_collect_kernel(const float4* __restrict__ pts,
        const int* __restrict__ perm, const float* __restrict__ thrbuf,
        unsigned int* __restrict__ cnt, unsigned short* __restrict__ survIdx) {
    __shared__ float4 lp[CHUNK2];                     // 8 KB -> 4 blocks/CU
    const int chunk = blockIdx.x, sg = blockIdx.y, b = blockIdx.z;
    const float4* pb = pts + b * PN;
    const int pbase = chunk * CHUNK2;
    for (int i = threadIdx.x; i < CHUNK2; i += 256) lp[i] = pb[pbase + i];
    __syncthreads();
    const int s = sg * 256 + threadIdx.x;
    const int bs = b * SN + s;
    const float4 qp = pb[perm[bs]];
    const float thr = thrbuf[bs];
    for (int c = 0; c < CHUNK2; ++c) {
        float4 pp = lp[c];
        float dx = qp.x - pp.x, dy = qp.y - pp.y, dz = qp.z - pp.z;
        float dd = dx * dx + dy * dy + dz * dz;
        if (dd < thr) {
            unsigned int slot = atomicAdd(&cnt[bs], 1u);
            if (slot < SCAP) survIdx[(size_t)bs * SCAP + slot] = (unsigned short)(pbase + c);
        }
    }
}

// ---------------- K3: exact f64 top-16 over survivors -> knn[b][rank][s] ----------------
// Survivor-list order is race-dependent, but the full-key sort makes output order-invariant.
__global__ void knn_exact_kernel(const float4* __restrict__ pts, const int* __restrict__ perm,
        const unsigned int* __restrict__ cnt, const unsigned short* __restrict__ survIdx,
        int* __restrict__ knn) {
    int t = blockIdx.x * 256 + threadIdx.x;           // 0 .. 2*SN-1
    int b = t >> 13, s = t & (SN - 1);
    const int bs = b * SN + s;
    const float4* pb = pts + b * PN;
    const float4 qp = pb[perm[bs]];
    const double qx = qp.x, qy = qp.y, qz = qp.z;
    int n = cnt[bs]; if (n > SCAP) n = SCAP;
    long long kv[16];
#pragma unroll
    for (int i = 0; i < 16; ++i) kv[i] = KEY_SENTINEL;
    const unsigned short* sl = survIdx + (size_t)bs * SCAP;
    for (int u = 0; u < n; ++u) {
        int c = sl[u];
        float4 pp = pb[c];
        double dx = qx - (double)pp.x;
        double dy = qy - (double)pp.y;
        double dz = qz - (double)pp.z;
        double dd = dx * dx + dy * dy + dz * dz;
        long long sc = (long long)floor(-dd * PD_SCALE);
        long long kk = (sc << 13) | (long long)(8191 - c);
        if (kk > kv[15]) {
#pragma unroll
            for (int i = 15; i > 0; --i) {
                bool sh = kk > kv[i - 1];
                kv[i] = sh ? kv[i - 1] : ((kk > kv[i]) ? kk : kv[i]);
            }
            if (kk > kv[0]) kv[0] = kk;
        }
    }
    int* ob = knn + (size_t)b * (SN * KNB);
#pragma unroll
    for (int r = 0; r < KNB; ++r)
        ob[(size_t)r * SN + s] = 8191 - (int)(kv[r] & 8191);
}

// ---------------- kernel 4: GroupNorm statistics ----------------
__global__ __launch_bounds__(256) void stats_kernel(const float* __restrict__ x,
        const int* __restrict__ knn, const float* __restrict__ w_pe,
        const float* __restrict__ w_conv, float* __restrict__ wavepart) {
    const int blk = blockIdx.x;                       // 0..255
    const int b = blockIdx.y;
    const int w = threadIdx.x >> 6, l = threadIdx.x & 63;
    float wr[10];
#pragma unroll
    for (int c = 0; c < 10; ++c) wr[c] = 0.f;
    if (l < 32) {
#pragma unroll
        for (int c = 0; c < 4; ++c) wr[c] = w_conv[l * 4 + c];
    } else {
#pragma unroll
        for (int c = 0; c < 10; ++c) wr[c] = w_pe[(l - 32) * 10 + c];
    }
    const float* xb = x + (size_t)b * 4 * PN;
    const int* kb = knn + (size_t)b * (SN * KNB);
    float s1 = 0.f, s2 = 0.f;
    const int nbase = blk * 512 + w * 128;
#pragma unroll 2
    for (int it = 0; it < 128; ++it) {
        int n = nbase + it;
        int i  = kb[n];
        int i0 = kb[n & ~15];
        float xa0 = xb[i], xa1 = xb[PN + i], xa2 = xb[2 * PN + i], xa3 = xb[3 * PN + i];
        float xc0 = xb[i0], xc1 = xb[PN + i0], xc2 = xb[2 * PN + i0];
        float d0 = xa0 - xc0, d1 = xa1 - xc1, d2 = xa2 - xc2;
        float dd = d0 * d0; dd += d1 * d1; dd += d2 * d2;
        float temp = sqrtf(fmaxf(dd, 1e-12f));
        float r;
        if (l < 32) {
            r = wr[0] * xa0 + wr[1] * xa1 + wr[2] * xa2 + wr[3] * xa3;
        } else {
            r = wr[0] * xa0 + wr[1] * xa1 + wr[2] * xa2
              + wr[3] * xc0 + wr[4] * xc1 + wr[5] * xc2
              + wr[6] * d0 + wr[7] * d1 + wr[8] * d2 + wr[9] * temp;
        }
        s1 += r;
        s2 += r * r;
    }
    const int wslot = blk * 4 + w;                    // 0..1023
    wavepart[((size_t)b * 1024 + wslot) * 128 + l] = s1;
    wavepart[((size_t)b * 1024 + wslot) * 128 + 64 + l] = s2;
}

// ---------------- kernel 5: finalize stats -> per-channel scale/shift ----------------
__global__ void finalize_kernel(const float* __restrict__ wavepart,
        const float* __restrict__ g_pe, const float* __restrict__ b_pe,
        const float* __restrict__ g_conv, const float* __restrict__ b_conv,
        float* __restrict__ scsh) {
    const int t = threadIdx.x;                        // 0..255
    const int b = t >> 7, k = t & 127;
    float acc = 0.f;
    for (int w = 0; w < 1024; ++w) acc += wavepart[((size_t)b * 1024 + w) * 128 + k];
    __shared__ float sums[2][128];
    sums[b][k] = acc;
    __syncthreads();
    if (k < 64) {
        const float N = 131072.f;
        float mean = sums[b][k] / N;
        float var = sums[b][64 + k] / N - mean * mean;
        float rstd = 1.0f / sqrtf(var + 1e-5f);
        float gam = (k < 32) ? g_conv[k] : g_pe[k - 32];
        float bet = (k < 32) ? b_conv[k] : b_pe[k - 32];
        float sc = gam * rstd;
        scsh[(b * 64 + k) * 2 + 0] = sc;
        scsh[(b * 64 + k) * 2 + 1] = bet - mean * sc;
    }
}

// ---------------- kernel 6: fused feature/attention/output ----------------
__global__ __launch_bounds__(256) void fused_main_kernel(
        const float* __restrict__ x, const int* __restrict__ knn,
        const float* __restrict__ w_pe, const float* __restrict__ w_conv,
        const float* __restrict__ w_att1, const float* __restrict__ w_att2,
        const float* __restrict__ w_b1, const float* __restrict__ w_b2,
        const float* __restrict__ scsh, float* __restrict__ out) {
    __shared__ float wb1T[64 * 64];                   // [c][o]
    __shared__ float wb2T[4 * 64];                    // [c][o]
    for (int i = threadIdx.x; i < 64 * 64; i += 256) wb1T[(i & 63) * 64 + (i >> 6)] = w_b1[i];
    { int i = threadIdx.x; wb2T[(i & 3) * 64 + (i >> 2)] = w_b2[i]; }
    __syncthreads();
    const int gidx = blockIdx.x;                      // 0..1023
    const int b = gidx >> 9;
    const int sb = (gidx & 511) << 4;
    const int l = threadIdx.x & 63;
    const int w = threadIdx.x >> 6;
    const int g = l >> 4, j = l & 15;
    const int s = sb + (w << 2) + g;
    const int srcl = g << 4;
    const float* xb = x + (size_t)b * 4 * PN;
    const int i1 = knn[(size_t)b * (SN * KNB) + (size_t)s * KNB + j];
    float xa0 = xb[i1], xa1 = xb[PN + i1], xa2 = xb[2 * PN + i1], xa3 = xb[3 * PN + i1];
    float xc0 = __shfl(xa0, srcl), xc1 = __shfl(xa1, srcl);
    float xc2 = __shfl(xa2, srcl), xc3 = __shfl(xa3, srcl);
    float d0 = xa0 - xc0, d1 = xa1 - xc1, d2 = xa2 - xc2;
    float dd = d0 * d0; dd += d1 * d1; dd += d2 * d2;
    float temp = sqrtf(fmaxf(dd, 1e-12f));
    float pem[10] = {xa0, xa1, xa2, xc0, xc1, xc2, d0, d1, d2, temp};
    float f[64];
    const float* ssb = scsh + b * 128;
#pragma unroll
    for (int o = 0; o < 32; ++o) {
        float r = w_conv[o * 4 + 0] * xa0;
        r += w_conv[o * 4 + 1] * xa1;
        r += w_conv[o * 4 + 2] * xa2;
        r += w_conv[o * 4 + 3] * xa3;
        r = r * ssb[o * 2 + 0] + ssb[o * 2 + 1];
        f[o] = (r >= 0.f) ? r : 0.2f * r;
    }
#pragma unroll
    for (int o = 0; o < 32; ++o) {
        float r = 0.f;
#pragma unroll
        for (int c = 0; c < 10; ++c) r += w_pe[o * 10 + c] * pem[c];
        r = r * ssb[(32 + o) * 2 + 0] + ssb[(32 + o) * 2 + 1];
        f[32 + o] = (r >= 0.f) ? r : 0.2f * r;
    }
    float logit = 0.f;
#pragma unroll 2
    for (int o = 0; o < 32; ++o) {
        float a = 0.f;
#pragma unroll
        for (int c = 0; c < 64; ++c) a += w_att1[o * 64 + c] * f[c];
        a = (a >= 0.f) ? a : 0.2f * a;
        logit += w_att2[o] * a;
    }
    float mx = logit;
    mx = fmaxf(mx, __shfl_xor(mx, 1));
    mx = fmaxf(mx, __shfl_xor(mx, 2));
    mx = fmaxf(mx, __shfl_xor(mx, 4));
    mx = fmaxf(mx, __shfl_xor(mx, 8));
    float e = expf(logit - mx);
    float se = e;
    se += __shfl_xor(se, 1);
    se += __shfl_xor(se, 2);
    se += __shfl_xor(se, 4);
    se += __shfl_xor(se, 8);
    float att = e / se;
#pragma unroll
    for (int c = 0; c < 64; ++c) {
        float v = f[c] * att;
        v += __shfl_xor(v, 1);
        v += __shfl_xor(v, 2);
        v += __shfl_xor(v, 4);
        v += __shfl_xor(v, 8);
        f[c] = v;
    }
    float o0 = 0.f, o1 = 0.f, o2 = 0.f, o3 = 0.f;
#pragma unroll
    for (int c = 0; c < 64; ++c) {
        float4 wv = *reinterpret_cast<const float4*>(&wb1T[c * 64 + 4 * j]);
        o0 += wv.x * f[c]; o1 += wv.y * f[c]; o2 += wv.z * f[c]; o3 += wv.w * f[c];
    }
    {
        float4 wv = *reinterpret_cast<const float4*>(&wb2T[0 * 64 + 4 * j]);
        o0 += wv.x * xc0; o1 += wv.y * xc0; o2 += wv.z * xc0; o3 += wv.w * xc0;
        wv = *reinterpret_cast<const float4*>(&wb2T[1 * 64 + 4 * j]);
        o0 += wv.x * xc1; o1 += wv.y * xc1; o2 += wv.z * xc1; o3 += wv.w * xc1;
        wv = *reinterpret_cast<const float4*>(&wb2T[2 * 64 + 4 * j]);
        o0 += wv.x * xc2; o1 += wv.y * xc2; o2 += wv.z * xc2; o3 += wv.w * xc2;
        wv = *reinterpret_cast<const float4*>(&wb2T[3 * 64 + 4 * j]);
        o0 += wv.x * xc3; o1 += wv.y * xc3; o2 += wv.z * xc3; o3 += wv.w * xc3;
    }
    o0 = (o0 >= 0.f) ? o0 : 0.1f * o0;
    o1 = (o1 >= 0.f) ? o1 : 0.1f * o1;
    o2 = (o2 >= 0.f) ? o2 : 0.1f * o2;
    o3 = (o3 >= 0.f) ? o3 : 0.1f * o3;
    float* ob = out + (size_t)b * 67 * SN;
    const int oc = 3 + 4 * j;
    ob[(size_t)(oc + 0) * SN + s] = o0;
    ob[(size_t)(oc + 1) * SN + s] = o1;
    ob[(size_t)(oc + 2) * SN + s] = o2;
    ob[(size_t)(oc + 3) * SN + s] = o3;
    if (j < 3) ob[(size_t)j * SN + s] = (j == 0) ? xc0 : ((j == 1) ? xc1 : xc2);
}

extern "C" void kernel_launch(void* const* d_in, const int* in_sizes, int n_in,
                              void* d_out, int out_size, void* d_ws, size_t ws_size,
                              hipStream_t stream) {
    (void)in_sizes; (void)n_in; (void)out_size; (void)ws_size;
    const float* x      = (const float*)d_in[0];
    const float* rnd    = (const float*)d_in[1];
    const float* w_pe   = (const float*)d_in[2];
    const float* g_pe   = (const float*)d_in[3];
    const float* b_pe   = (const float*)d_in[4];
    const float* w_conv = (const float*)d_in[5];
    const float* g_conv = (const float*)d_in[6];
    const float* b_conv = (const float*)d_in[7];
    const float* w_att1 = (const float*)d_in[8];
    const float* w_att2 = (const float*)d_in[9];
    const float* w_b1   = (const float*)d_in[10];
    const float* w_b2   = (const float*)d_in[11];
    float* out = (float*)d_out;
    char* ws = (char*)d_ws;
    // workspace carve-up (bytes), peak ~10.4 MB.
    // vv (8 MB) is dead after knn_thr_kernel; knn and wavept alias into its region.
    float4*         pts     = (float4*)        (ws + 0);          //   262,144
    int*            perm    = (int*)           (ws + 262144);     //    65,536
    float*          vv      = (float*)         (ws + 327680);     // 8,388,608 [dead after K1.5]
    int*            knn     = (int*)           (ws + 327680);     // 1,048,576 (alias vv; written by K3)
    float*          wavept  = (float*)         (ws + 1376256);    // 1,048,576 (alias vv tail)
    float*          thrbuf  = (float*)         (ws + 8716288);    //    65,536
    unsigned int*   cnt     = (unsigned int*)  (ws + 8781824);    //    65,536
    unsigned short* survIdx = (unsigned short*)(ws + 8847360);    // 1,572,864
    float*          scsh    = (float*)         (ws + 10813440);   //     1,024

    pack_pts_kernel<<<64, 256, 0, stream>>>(x, pts);
    argsort_kernel<<<2, 1024, 0, stream>>>(rnd, perm);
    knn_val16_kernel<<<dim3(NCH1, 32, 2), 256, 0, stream>>>(pts, perm, vv);
    knn_thr_kernel<<<64, 256, 0, stream>>>(vv, thrbuf);
    hipMemsetAsync(cnt, 0, 2 * SN * sizeof(unsigned int), stream);
    knn_collect_kernel<<<dim3(NCH2, 32, 2), 256, 0, stream>>>(pts, perm, thrbuf, cnt, survIdx);
    knn_exact_kernel<<<64, 256, 0, stream>>>(pts, perm, cnt, survIdx, knn);
    stats_kernel<<<dim3(256, 2), 256, 0, stream>>>(x, knn, w_pe, w_conv, wavept);
    finalize_kernel<<<1, 256, 0, stream>>>(wavept, g_pe, b_pe, g_conv, b_conv, scsh);
    fused_main_kernel<<<1024, 256, 0, stream>>>(x, knn, w_pe, w_conv, w_att1, w_att2,
                                                w_b1, w_b2, scsh, out);
}

// Round 8
// 334.255 us; speedup vs baseline: 3.4228x; 1.2876x over previous
//
#include <hip/hip_runtime.h>
#include <stdint.h>

#define PN 8192
#define SN 8192
#define KNB 16
#define NCH1 8
#define CHUNK1 (PN / NCH1)    // 1024
#define NCH2 16
#define CHUNK2 (PN / NCH2)    // 512
#define SCAP 48
#define MARGIN 1.0e-3f
#define NRCH 8
#define RCH (PN / NRCH)       // 1024

#define KEY_SENTINEL ((long long)0x8000000000000000ULL)
#define PD_SCALE 2199023255552.0   // 2^41: dd<1024 -> |scaled|<2^51; <<13 fits i64

// ---------------- helpers: branch-free sorted-16 maintenance ----------------
__device__ __forceinline__ void bitonic_sort16(float* b) {
#pragma unroll
    for (int k = 2; k <= 16; k <<= 1) {
#pragma unroll
        for (int j = k >> 1; j > 0; j >>= 1) {
#pragma unroll
            for (int i = 0; i < 16; ++i) {
                int l = i ^ j;
                if (l > i) {
                    float lo = fminf(b[i], b[l]), hi = fmaxf(b[i], b[l]);
                    bool up = ((i & k) == 0);
                    b[i] = up ? lo : hi;
                    b[l] = up ? hi : lo;
                }
            }
        }
    }
}
// r, b ascending sorted-16 -> r = lowest 16 of union, ascending.
__device__ __forceinline__ void merge16(float* r, const float* b) {
    float t[16];
#pragma unroll
    for (int i = 0; i < 16; ++i) t[i] = fminf(r[i], b[15 - i]);   // bitonic
#pragma unroll
    for (int j = 8; j > 0; j >>= 1) {
#pragma unroll
        for (int i = 0; i < 16; ++i) {
            int l = i ^ j;
            if (l > i) {
                float lo = fminf(t[i], t[l]), hi = fmaxf(t[i], t[l]);
                t[i] = lo; t[l] = hi;
            }
        }
    }
#pragma unroll
    for (int i = 0; i < 16; ++i) r[i] = t[i];
}

// ---------------- kernel 0: pack points (x,y,z,0) ----------------
__global__ void pack_pts_kernel(const float* __restrict__ x, float4* __restrict__ pts) {
    int i = blockIdx.x * 256 + threadIdx.x;           // 0 .. 2*PN-1
    int b = i >> 13, p = i & (PN - 1);
    const float* xb = x + (size_t)b * 4 * PN;
    pts[i] = make_float4(xb[p], xb[PN + p], xb[2 * PN + p], 0.f);
}

// ---------------- argsort stage A: partial rank counts (rank-by-counting) ----------------
// Stable argsort == scatter by rank of distinct key (rand_bits << 13 | idx).
// Thread owns element i; scans a 1024-candidate chunk from LDS (u64 broadcast reads).
__global__ __launch_bounds__(256) void rank_count_kernel(const float* __restrict__ rnd,
        unsigned short* __restrict__ rcnt) {
    __shared__ unsigned long long lk[RCH];            // 8 KB
    const int chunk = blockIdx.x, sg = blockIdx.y, b = blockIdx.z;
    const unsigned int* rb = (const unsigned int*)rnd + b * PN;   // [0,1) floats: bits order-preserving
    const int cbase = chunk * RCH;
    for (int c = threadIdx.x; c < RCH; c += 256) {
        int j = cbase + c;
        lk[c] = ((unsigned long long)rb[j] << 13) | (unsigned)j;
    }
    __syncthreads();
    const int i = sg * 256 + threadIdx.x;
    const unsigned long long ki = ((unsigned long long)rb[i] << 13) | (unsigned)i;
    int cnt = 0;
#pragma unroll 8
    for (int c = 0; c < RCH; ++c) cnt += (lk[c] < ki) ? 1 : 0;
    rcnt[(((size_t)(b * NRCH + chunk)) << 13) + i] = (unsigned short)cnt;
}

// ---------------- argsort stage B: sum partials, scatter perm[rank] = i ----------------
// Ranks are a permutation (keys distinct) -> every perm slot written -> deterministic.
__global__ void rank_scatter_kernel(const unsigned short* __restrict__ rcnt,
                                    int* __restrict__ perm) {
    int t = blockIdx.x * 256 + threadIdx.x;           // 0 .. 2*PN-1
    int b = t >> 13, i = t & (PN - 1);
    int rank = 0;
#pragma unroll
    for (int ch = 0; ch < NRCH; ++ch)
        rank += rcnt[(((size_t)(b * NRCH + ch)) << 13) + i];
    perm[b * PN + rank] = i;
}

// ---------------- K1: per-(sample, 1/8-chunk) sorted f32 top-16 distances ----------------
// Batch-16 sorting network; zero branches, zero LDS conflicts (broadcast reads).
__global__ __launch_bounds__(256) void knn_val16_kernel(const float4* __restrict__ pts,
        const int* __restrict__ perm, float* __restrict__ vv) {
    __shared__ float4 lp[CHUNK1];                     // 16 KB
    const int chunk = blockIdx.x, sg = blockIdx.y, b = blockIdx.z;
    const float4* pb = pts + b * PN;
    const int pbase = chunk * CHUNK1;
    for (int i = threadIdx.x; i < CHUNK1; i += 256) lp[i] = pb[pbase + i];
    __syncthreads();
    const int s = sg * 256 + threadIdx.x;
    const float4 qp = pb[perm[b * PN + s]];
    float r[16];
#pragma unroll
    for (int i = 0; i < 16; ++i) r[i] = 3.0e38f;
    for (int t = 0; t < CHUNK1; t += 16) {
        float bv[16];
#pragma unroll
        for (int u = 0; u < 16; ++u) {
            float4 pp = lp[t + u];
            float dx = qp.x - pp.x, dy = qp.y - pp.y, dz = qp.z - pp.z;
            bv[u] = dx * dx + dy * dy + dz * dz;
        }
        bitonic_sort16(bv);
        merge16(r, bv);
    }
    float* ov = vv + ((size_t)(b * NCH1 + chunk) * 16) * SN + s;
#pragma unroll
    for (int i = 0; i < 16; ++i) ov[(size_t)i * SN] = r[i];
}

// ---------------- K1.5: merge 8 sorted chunk value-lists -> global v15 -> thr ----------------
__global__ void knn_thr_kernel(const float* __restrict__ vv, float* __restrict__ thrbuf) {
    int t = blockIdx.x * 256 + threadIdx.x;           // 0 .. 2*SN-1
    int b = t >> 13, s = t & (SN - 1);
    float r[16], bl[16];
    const float* v0 = vv + ((size_t)(b * NCH1) * 16) * SN + s;
#pragma unroll
    for (int i = 0; i < 16; ++i) r[i] = v0[(size_t)i * SN];
    for (int ch = 1; ch < NCH1; ++ch) {
        const float* vc = vv + ((size_t)(b * NCH1 + ch) * 16) * SN + s;
#pragma unroll
        for (int i = 0; i < 16; ++i) bl[i] = vc[(size_t)i * SN];
        merge16(r, bl);
    }
    thrbuf[b * SN + s] = r[15] + MARGIN;              // >= true global d16 (superset proof)
}

// ---------------- K2: collect survivors (dd < thr) into global per-sample lists ----------------
__global__ __launch_bounds__(256) void knn_collect_kernel(const float4* __restrict__ pts,
        const int* __restrict__ perm, const float* __restrict__ thrbuf,
        unsigned int* __restrict__ cnt, unsigned short* __restrict__ survIdx) {
    __shared__ float4 lp[CHUNK2];                     // 8 KB -> 4 blocks/CU
    const int chunk = blockIdx.x, sg = blockIdx.y, b = blockIdx.z;
    const float4* pb = pts + b * PN;
    const int pbase = chunk * CHUNK2;
    for (int i = threadIdx.x; i < CHUNK2; i += 256) lp[i] = pb[pbase + i];
    __syncthreads();
    const int s = sg * 256 + threadIdx.x;
    const int bs = b * SN + s;
    const float4 qp = pb[perm[bs]];
    const float thr = thrbuf[bs];
    for (int c = 0; c < CHUNK2; ++c) {
        float4 pp = lp[c];
        float dx = qp.x - pp.x, dy = qp.y - pp.y, dz = qp.z - pp.z;
        float dd = dx * dx + dy * dy + dz * dz;
        if (dd < thr) {
            unsigned int slot = atomicAdd(&cnt[bs], 1u);
            if (slot < SCAP) survIdx[(size_t)bs * SCAP + slot] = (unsigned short)(pbase + c);
        }
    }
}

// ---------------- K3: exact f64 top-16 over survivors -> knn[b][rank][s] ----------------
// Survivor-list order is race-dependent, but the full-key sort makes output order-invariant.
__global__ void knn_exact_kernel(const float4* __restrict__ pts, const int* __restrict__ perm,
        const unsigned int* __restrict__ cnt, const unsigned short* __restrict__ survIdx,
        int* __restrict__ knn) {
    int t = blockIdx.x * 256 + threadIdx.x;           // 0 .. 2*SN-1
    int b = t >> 13, s = t & (SN - 1);
    const int bs = b * SN + s;
    const float4* pb = pts + b * PN;
    const float4 qp = pb[perm[bs]];
    const double qx = qp.x, qy = qp.y, qz = qp.z;
    int n = cnt[bs]; if (n > SCAP) n = SCAP;
    long long kv[16];
#pragma unroll
    for (int i = 0; i < 16; ++i) kv[i] = KEY_SENTINEL;
    const unsigned short* sl = survIdx + (size_t)bs * SCAP;
    for (int u = 0; u < n; ++u) {
        int c = sl[u];
        float4 pp = pb[c];
        double dx = qx - (double)pp.x;
        double dy = qy - (double)pp.y;
        double dz = qz - (double)pp.z;
        double dd = dx * dx + dy * dy + dz * dz;
        long long sc = (long long)floor(-dd * PD_SCALE);
        long long kk = (sc << 13) | (long long)(8191 - c);
        if (kk > kv[15]) {
#pragma unroll
            for (int i = 15; i > 0; --i) {
                bool sh = kk > kv[i - 1];
                kv[i] = sh ? kv[i - 1] : ((kk > kv[i]) ? kk : kv[i]);
            }
            if (kk > kv[0]) kv[0] = kk;
        }
    }
    int* ob = knn + (size_t)b * (SN * KNB);
#pragma unroll
    for (int r = 0; r < KNB; ++r)
        ob[(size_t)r * SN + s] = 8191 - (int)(kv[r] & 8191);
}

// ---------------- kernel 4: GroupNorm statistics ----------------
__global__ __launch_bounds__(256) void stats_kernel(const float* __restrict__ x,
        const int* __restrict__ knn, const float* __restrict__ w_pe,
        const float* __restrict__ w_conv, float* __restrict__ wavepart) {
    const int blk = blockIdx.x;                       // 0..255
    const int b = blockIdx.y;
    const int w = threadIdx.x >> 6, l = threadIdx.x & 63;
    float wr[10];
#pragma unroll
    for (int c = 0; c < 10; ++c) wr[c] = 0.f;
    if (l < 32) {
#pragma unroll
        for (int c = 0; c < 4; ++c) wr[c] = w_conv[l * 4 + c];
    } else {
#pragma unroll
        for (int c = 0; c < 10; ++c) wr[c] = w_pe[(l - 32) * 10 + c];
    }
    const float* xb = x + (size_t)b * 4 * PN;
    const int* kb = knn + (size_t)b * (SN * KNB);
    float s1 = 0.f, s2 = 0.f;
    const int nbase = blk * 512 + w * 128;
#pragma unroll 2
    for (int it = 0; it < 128; ++it) {
        int n = nbase + it;
        int i  = kb[n];
        int i0 = kb[n & ~15];
        float xa0 = xb[i], xa1 = xb[PN + i], xa2 = xb[2 * PN + i], xa3 = xb[3 * PN + i];
        float xc0 = xb[i0], xc1 = xb[PN + i0], xc2 = xb[2 * PN + i0];
        float d0 = xa0 - xc0, d1 = xa1 - xc1, d2 = xa2 - xc2;
        float dd = d0 * d0; dd += d1 * d1; dd += d2 * d2;
        float temp = sqrtf(fmaxf(dd, 1e-12f));
        float r;
        if (l < 32) {
            r = wr[0] * xa0 + wr[1] * xa1 + wr[2] * xa2 + wr[3] * xa3;
        } else {
            r = wr[0] * xa0 + wr[1] * xa1 + wr[2] * xa2
              + wr[3] * xc0 + wr[4] * xc1 + wr[5] * xc2
              + wr[6] * d0 + wr[7] * d1 + wr[8] * d2 + wr[9] * temp;
        }
        s1 += r;
        s2 += r * r;
    }
    const int wslot = blk * 4 + w;                    // 0..1023
    wavepart[((size_t)b * 1024 + wslot) * 128 + l] = s1;
    wavepart[((size_t)b * 1024 + wslot) * 128 + 64 + l] = s2;
}

// ---------------- kernel 5: finalize stats -> per-channel scale/shift ----------------
__global__ void finalize_kernel(const float* __restrict__ wavepart,
        const float* __restrict__ g_pe, const float* __restrict__ b_pe,
        const float* __restrict__ g_conv, const float* __restrict__ b_conv,
        float* __restrict__ scsh) {
    const int t = threadIdx.x;                        // 0..255
    const int b = t >> 7, k = t & 127;
    float acc = 0.f;
    for (int w = 0; w < 1024; ++w) acc += wavepart[((size_t)b * 1024 + w) * 128 + k];
    __shared__ float sums[2][128];
    sums[b][k] = acc;
    __syncthreads();
    if (k < 64) {
        const float N = 131072.f;
        float mean = sums[b][k] / N;
        float var = sums[b][64 + k] / N - mean * mean;
        float rstd = 1.0f / sqrtf(var + 1e-5f);
        float gam = (k < 32) ? g_conv[k] : g_pe[k - 32];
        float bet = (k < 32) ? b_conv[k] : b_pe[k - 32];
        float sc = gam * rstd;
        scsh[(b * 64 + k) * 2 + 0] = sc;
        scsh[(b * 64 + k) * 2 + 1] = bet - mean * sc;
    }
}

// ---------------- kernel 6: fused feature/attention/output ----------------
__global__ __launch_bounds__(256) void fused_main_kernel(
        const float* __restrict__ x, const int* __restrict__ knn,
        const float* __restrict__ w_pe, const float* __restrict__ w_conv,
        const float* __restrict__ w_att1, const float* __restrict__ w_att2,
        const float* __restrict__ w_b1, const float* __restrict__ w_b2,
        const float* __restrict__ scsh, float* __restrict__ out) {
    __shared__ float wb1T[64 * 64];                   // [c][o]
    __shared__ float wb2T[4 * 64];                    // [c][o]
    for (int i = threadIdx.x; i < 64 * 64; i += 256) wb1T[(i & 63) * 64 + (i >> 6)] = w_b1[i];
    { int i = threadIdx.x; wb2T[(i & 3) * 64 + (i >> 2)] = w_b2[i]; }
    __syncthreads();
    const int gidx = blockIdx.x;                      // 0..1023
    const int b = gidx >> 9;
    const int sb = (gidx & 511) << 4;
    const int l = threadIdx.x & 63;
    const int w = threadIdx.x >> 6;
    const int g = l >> 4, j = l & 15;
    const int s = sb + (w << 2) + g;
    const int srcl = g << 4;
    const float* xb = x + (size_t)b * 4 * PN;
    const int i1 = knn[(size_t)b * (SN * KNB) + (size_t)s * KNB + j];
    float xa0 = xb[i1], xa1 = xb[PN + i1], xa2 = xb[2 * PN + i1], xa3 = xb[3 * PN + i1];
    float xc0 = __shfl(xa0, srcl), xc1 = __shfl(xa1, srcl);
    float xc2 = __shfl(xa2, srcl), xc3 = __shfl(xa3, srcl);
    float d0 = xa0 - xc0, d1 = xa1 - xc1, d2 = xa2 - xc2;
    float dd = d0 * d0; dd += d1 * d1; dd += d2 * d2;
    float temp = sqrtf(fmaxf(dd, 1e-12f));
    float pem[10] = {xa0, xa1, xa2, xc0, xc1, xc2, d0, d1, d2, temp};
    float f[64];
    const float* ssb = scsh + b * 128;
#pragma unroll
    for (int o = 0; o < 32; ++o) {
        float r = w_conv[o * 4 + 0] * xa0;
        r += w_conv[o * 4 + 1] * xa1;
        r += w_conv[o * 4 + 2] * xa2;
        r += w_conv[o * 4 + 3] * xa3;
        r = r * ssb[o * 2 + 0] + ssb[o * 2 + 1];
        f[o] = (r >= 0.f) ? r : 0.2f * r;
    }
#pragma unroll
    for (int o = 0; o < 32; ++o) {
        float r = 0.f;
#pragma unroll
        for (int c = 0; c < 10; ++c) r += w_pe[o * 10 + c] * pem[c];
        r = r * ssb[(32 + o) * 2 + 0] + ssb[(32 + o) * 2 + 1];
        f[32 + o] = (r >= 0.f) ? r : 0.2f * r;
    }
    float logit = 0.f;
#pragma unroll 2
    for (int o = 0; o < 32; ++o) {
        float a = 0.f;
#pragma unroll
        for (int c = 0; c < 64; ++c) a += w_att1[o * 64 + c] * f[c];
        a = (a >= 0.f) ? a : 0.2f * a;
        logit += w_att2[o] * a;
    }
    float mx = logit;
    mx = fmaxf(mx, __shfl_xor(mx, 1));
    mx = fmaxf(mx, __shfl_xor(mx, 2));
    mx = fmaxf(mx, __shfl_xor(mx, 4));
    mx = fmaxf(mx, __shfl_xor(mx, 8));
    float e = expf(logit - mx);
    float se = e;
    se += __shfl_xor(se, 1);
    se += __shfl_xor(se, 2);
    se += __shfl_xor(se, 4);
    se += __shfl_xor(se, 8);
    float att = e / se;
#pragma unroll
    for (int c = 0; c < 64; ++c) {
        float v = f[c] * att;
        v += __shfl_xor(v, 1);
        v += __shfl_xor(v, 2);
        v += __shfl_xor(v, 4);
        v += __shfl_xor(v, 8);
        f[c] = v;
    }
    float o0 = 0.f, o1 = 0.f, o2 = 0.f, o3 = 0.f;
#pragma unroll
    for (int c = 0; c < 64; ++c) {
        float4 wv = *reinterpret_cast<const float4*>(&wb1T[c * 64 + 4 * j]);
        o0 += wv.x * f[c]; o1 += wv.y * f[c]; o2 += wv.z * f[c]; o3 += wv.w * f[c];
    }
    {
        float4 wv = *reinterpret_cast<const float4*>(&wb2T[0 * 64 + 4 * j]);
        o0 += wv.x * xc0; o1 += wv.y * xc0; o2 += wv.z * xc0; o3 += wv.w * xc0;
        wv = *reinterpret_cast<const float4*>(&wb2T[1 * 64 + 4 * j]);
        o0 += wv.x * xc1; o1 += wv.y * xc1; o2 += wv.z * xc1; o3 += wv.w * xc1;
        wv = *reinterpret_cast<const float4*>(&wb2T[2 * 64 + 4 * j]);
        o0 += wv.x * xc2; o1 += wv.y * xc2; o2 += wv.z * xc2; o3 += wv.w * xc2;
        wv = *reinterpret_cast<const float4*>(&wb2T[3 * 64 + 4 * j]);
        o0 += wv.x * xc3; o1 += wv.y * xc3; o2 += wv.z * xc3; o3 += wv.w * xc3;
    }
    o0 = (o0 >= 0.f) ? o0 : 0.1f * o0;
    o1 = (o1 >= 0.f) ? o1 : 0.1f * o1;
    o2 = (o2 >= 0.f) ? o2 : 0.1f * o2;
    o3 = (o3 >= 0.f) ? o3 : 0.1f * o3;
    float* ob = out + (size_t)b * 67 * SN;
    const int oc = 3 + 4 * j;
    ob[(size_t)(oc + 0) * SN + s] = o0;
    ob[(size_t)(oc + 1) * SN + s] = o1;
    ob[(size_t)(oc + 2) * SN + s] = o2;
    ob[(size_t)(oc + 3) * SN + s] = o3;
    if (j < 3) ob[(size_t)j * SN + s] = (j == 0) ? xc0 : ((j == 1) ? xc1 : xc2);
}

extern "C" void kernel_launch(void* const* d_in, const int* in_sizes, int n_in,
                              void* d_out, int out_size, void* d_ws, size_t ws_size,
                              hipStream_t stream) {
    (void)in_sizes; (void)n_in; (void)out_size; (void)ws_size;
    const float* x      = (const float*)d_in[0];
    const float* rnd    = (const float*)d_in[1];
    const float* w_pe   = (const float*)d_in[2];
    const float* g_pe   = (const float*)d_in[3];
    const float* b_pe   = (const float*)d_in[4];
    const float* w_conv = (const float*)d_in[5];
    const float* g_conv = (const float*)d_in[6];
    const float* b_conv = (const float*)d_in[7];
    const float* w_att1 = (const float*)d_in[8];
    const float* w_att2 = (const float*)d_in[9];
    const float* w_b1   = (const float*)d_in[10];
    const float* w_b2   = (const float*)d_in[11];
    float* out = (float*)d_out;
    char* ws = (char*)d_ws;
    // workspace carve-up (bytes), peak ~10.4 MB.
    // vv (8 MB) region is time-shared: rcnt (argsort partials, dead after scatter),
    // then vv (dead after K1.5), then knn + wavept.
    float4*         pts     = (float4*)        (ws + 0);          //   262,144
    int*            perm    = (int*)           (ws + 262144);     //    65,536
    float*          vv      = (float*)         (ws + 327680);     // 8,388,608 [dead after K1.5]
    unsigned short* rcnt    = (unsigned short*)(ws + 327680);     //   262,144 (alias vv; dead after scatter)
    int*            knn     = (int*)           (ws + 327680);     // 1,048,576 (alias vv; written by K3)
    float*          wavept  = (float*)         (ws + 1376256);    // 1,048,576 (alias vv tail)
    float*          thrbuf  = (float*)         (ws + 8716288);    //    65,536
    unsigned int*   cnt     = (unsigned int*)  (ws + 8781824);    //    65,536
    unsigned short* survIdx = (unsigned short*)(ws + 8847360);    // 1,572,864
    float*          scsh    = (float*)         (ws + 10813440);   //     1,024

    pack_pts_kernel<<<64, 256, 0, stream>>>(x, pts);
    rank_count_kernel<<<dim3(NRCH, 32, 2), 256, 0, stream>>>(rnd, rcnt);
    rank_scatter_kernel<<<64, 256, 0, stream>>>(rcnt, perm);
    knn_val16_kernel<<<dim3(NCH1, 32, 2), 256, 0, stream>>>(pts, perm, vv);
    knn_thr_kernel<<<64, 256, 0, stream>>>(vv, thrbuf);
    hipMemsetAsync(cnt, 0, 2 * SN * sizeof(unsigned int), stream);
    knn_collect_kernel<<<dim3(NCH2, 32, 2), 256, 0, stream>>>(pts, perm, thrbuf, cnt, survIdx);
    knn_exact_kernel<<<64, 256, 0, stream>>>(pts, perm, cnt, survIdx, knn);
    stats_kernel<<<dim3(256, 2), 256, 0, stream>>>(x, knn, w_pe, w_conv, wavept);
    finalize_kernel<<<1, 256, 0, stream>>>(wavept, g_pe, b_pe, g_conv, b_conv, scsh);
    fused_main_kernel<<<1024, 256, 0, stream>>>(x, knn, w_pe, w_conv, w_att1, w_att2,
                                                w_b1, w_b2, scsh, out);
}